// Round 3
// baseline (1191.989 us; speedup 1.0000x reference)
//
#include <hip/hip_runtime.h>

#define EPS 1e-5f
#define NIN 9
#define F1 32
#define F2 64
#define NMOM 45
#define CHUNK 64

// ws float offsets
#define WS_S    0     // 9   sum x
#define WS_M    16    // 45  sum xx^T upper-tri
#define WS_S2   64    // 64  sum h2
#define WS_SS2  128   // 64  sum h2^2
#define WS_SC1  192   // 32  scale1
#define WS_SH1  224   // 32  folded shift1' = be1 - mean*scale1
#define WS_W1P  256   // 288 w1 * scale1
#define WS_SC2  544   // 64
#define WS_SH2  608   // 64

// ---------------- Pass A: x moments ----------------
__global__ __launch_bounds__(256, 4) void moments_kernel(
    const float* __restrict__ pts, float* __restrict__ ws, int N)
{
    float S[NIN], M[NMOM];
#pragma unroll
    for (int k = 0; k < NIN; ++k) S[k] = 0.f;
#pragma unroll
    for (int m = 0; m < NMOM; ++m) M[m] = 0.f;

    const int stride = gridDim.x * blockDim.x;
    for (int i = blockIdx.x * blockDim.x + threadIdx.x; i < N; i += stride) {
        const float* p = pts + (size_t)i * NIN;
        float x[NIN];
#pragma unroll
        for (int k = 0; k < NIN; ++k) x[k] = p[k];
        int m = 0;
#pragma unroll
        for (int k = 0; k < NIN; ++k) {
            S[k] += x[k];
#pragma unroll
            for (int l = k; l < NIN; ++l) { M[m] = fmaf(x[k], x[l], M[m]); ++m; }
        }
    }
    // 64-lane butterfly
#pragma unroll
    for (int off = 32; off > 0; off >>= 1) {
#pragma unroll
        for (int k = 0; k < NIN; ++k) S[k] += __shfl_xor(S[k], off, 64);
#pragma unroll
        for (int m = 0; m < NMOM; ++m) M[m] += __shfl_xor(M[m], off, 64);
    }
    __shared__ float red[64];
    if (threadIdx.x < 64) red[threadIdx.x] = 0.f;
    __syncthreads();
    if ((threadIdx.x & 63) == 0) {
#pragma unroll
        for (int k = 0; k < NIN; ++k) atomicAdd(&red[WS_S + k], S[k]);
#pragma unroll
        for (int m = 0; m < NMOM; ++m) atomicAdd(&red[WS_M + m], M[m]);
    }
    __syncthreads();
    if (threadIdx.x < 64) atomicAdd(&ws[threadIdx.x], red[threadIdx.x]);
}

// ---------------- finalize1: BN1 params from moments + fold weights ----------------
__global__ void finalize1_kernel(
    const float* __restrict__ w1, const float* __restrict__ b1,
    const float* __restrict__ g1, const float* __restrict__ be1,
    float* __restrict__ ws, float invN)
{
    __shared__ float sc1s[F1];
    const int j = threadIdx.x;
    if (j < F1) {
        float W[NIN];
        float P = 0.f;
#pragma unroll
        for (int k = 0; k < NIN; ++k) {
            W[k] = w1[k * F1 + j];
            P = fmaf(ws[WS_S + k], W[k], P);
        }
        float Q = 0.f;
        int m = 0;
#pragma unroll
        for (int k = 0; k < NIN; ++k) {
            Q = fmaf(ws[WS_M + m], W[k] * W[k], Q); ++m;
#pragma unroll
            for (int l = k + 1; l < NIN; ++l) {
                Q = fmaf(2.f * ws[WS_M + m], W[k] * W[l], Q); ++m;
            }
        }
        const float b = b1[j];
        const float mean = fmaf(P, invN, b);
        const float Eh2 = fmaf(fmaf(2.f * b, P, Q), invN, b * b);
        const float var = Eh2 - mean * mean;
        const float sc = g1[j] * rsqrtf(var + EPS);
        ws[WS_SC1 + j] = sc;
        ws[WS_SH1 + j] = be1[j] - mean * sc;
        sc1s[j] = sc;
    }
    __syncthreads();
    for (int m = threadIdx.x; m < NIN * F1; m += blockDim.x)
        ws[WS_W1P + m] = w1[m] * sc1s[m & (F1 - 1)];
}

__global__ void finalize2_kernel(
    const float* __restrict__ g2, const float* __restrict__ be2,
    float* __restrict__ ws, float invN)
{
    const int j = threadIdx.x;
    if (j < F2) {
        const float mean = ws[WS_S2 + j] * invN;
        const float var  = ws[WS_SS2 + j] * invN - mean * mean;
        const float sc   = g2[j] * rsqrtf(var + EPS);
        ws[WS_SC2 + j] = sc;
        ws[WS_SH2 + j] = be2[j] - mean * sc;
    }
}

// f1 = relu(x @ W1' + shift1'), W1'/shift1' staged in LDS (broadcast b128 reads)
__device__ __forceinline__ void compute_f1_lds(
    const float* __restrict__ p, const float* __restrict__ wl,
    float4* __restrict__ out4)
{
    float x[NIN];
#pragma unroll
    for (int k = 0; k < NIN; ++k) x[k] = p[k];
    const float4* W4  = (const float4*)wl;           // [k*8 + j4]
    const float4* SH4 = (const float4*)(wl + NIN * F1);
#pragma unroll
    for (int j4 = 0; j4 < 8; ++j4) {
        float4 h = SH4[j4];
#pragma unroll
        for (int k = 0; k < NIN; ++k) {
            const float4 w = W4[k * 8 + j4];
            h.x = fmaf(x[k], w.x, h.x);
            h.y = fmaf(x[k], w.y, h.y);
            h.z = fmaf(x[k], w.z, h.z);
            h.w = fmaf(x[k], w.w, h.w);
        }
        h.x = fmaxf(h.x, 0.f); h.y = fmaxf(h.y, 0.f);
        h.z = fmaxf(h.z, 0.f); h.w = fmaxf(h.w, 0.f);
        out4[j4] = h;
    }
}

// ---------------- Pass B: h2 stats (lane = feature, wave-autonomous 64-pt chunks) ----------------
__global__ __launch_bounds__(256, 4) void stats2_kernel(
    const float* __restrict__ pts, const float* __restrict__ w2,
    const float* __restrict__ b2, float* __restrict__ ws, int N)
{
    __shared__ float4 wlds4[80];                 // 288 W1' + 32 shift1'
    __shared__ float4 f1t[4][CHUNK * 9];         // per-wave rows: 8 used + 1 pad float4
    float* wl = (float*)wlds4;
    for (int m = threadIdx.x; m < NIN * F1; m += 256) wl[m] = ws[WS_W1P + m];
    if (threadIdx.x < F1) wl[NIN * F1 + threadIdx.x] = ws[WS_SH1 + threadIdx.x];

    const int lane = threadIdx.x & 63, wv = threadIdx.x >> 6;
    float w2col[F1];
#pragma unroll
    for (int k = 0; k < F1; ++k) w2col[k] = w2[k * F2 + lane];
    const float b2j = b2[lane];
    __syncthreads();

    float s = 0.f, ss = 0.f;
    const int nchunks = (N + CHUNK - 1) / CHUNK;
    for (int c = blockIdx.x * 4 + wv; c < nchunks; c += gridDim.x * 4) {
        const int base = c * CHUNK;
        const int i = base + lane;
        if (i < N) compute_f1_lds(pts + (size_t)i * NIN, wl, &f1t[wv][lane * 9]);
        const int n = min(CHUNK, N - base);
        int p = 0;
        for (; p + 1 < n; p += 2) {
            const float4* r0 = &f1t[wv][p * 9];
            const float4* r1 = &f1t[wv][(p + 1) * 9];
            float h0 = b2j, h1 = b2j;
#pragma unroll
            for (int k4 = 0; k4 < 8; ++k4) {
                const float4 a = r0[k4], b = r1[k4];
                h0 = fmaf(a.x, w2col[4*k4+0], h0); h1 = fmaf(b.x, w2col[4*k4+0], h1);
                h0 = fmaf(a.y, w2col[4*k4+1], h0); h1 = fmaf(b.y, w2col[4*k4+1], h1);
                h0 = fmaf(a.z, w2col[4*k4+2], h0); h1 = fmaf(b.z, w2col[4*k4+2], h1);
                h0 = fmaf(a.w, w2col[4*k4+3], h0); h1 = fmaf(b.w, w2col[4*k4+3], h1);
            }
            s += h0; ss = fmaf(h0, h0, ss);
            s += h1; ss = fmaf(h1, h1, ss);
        }
        if (p < n) {
            const float4* r0 = &f1t[wv][p * 9];
            float h0 = b2j;
#pragma unroll
            for (int k4 = 0; k4 < 8; ++k4) {
                const float4 a = r0[k4];
                h0 = fmaf(a.x, w2col[4*k4+0], h0);
                h0 = fmaf(a.y, w2col[4*k4+1], h0);
                h0 = fmaf(a.z, w2col[4*k4+2], h0);
                h0 = fmaf(a.w, w2col[4*k4+3], h0);
            }
            s += h0; ss = fmaf(h0, h0, ss);
        }
    }
    __shared__ float red[2 * F2];
    if (threadIdx.x < 2 * F2) red[threadIdx.x] = 0.f;
    __syncthreads();
    atomicAdd(&red[lane], s);
    atomicAdd(&red[F2 + lane], ss);
    __syncthreads();
    if (threadIdx.x < F2) {
        atomicAdd(&ws[WS_S2 + threadIdx.x],  red[threadIdx.x]);
        atomicAdd(&ws[WS_SS2 + threadIdx.x], red[F2 + threadIdx.x]);
    }
}

// ---------------- Pass C: feat2 + segment atomicMax ----------------
__global__ __launch_bounds__(256, 4) void scatter_kernel(
    const float* __restrict__ pts, const int* __restrict__ idx,
    const float* __restrict__ w2, const float* __restrict__ b2,
    const float* __restrict__ ws, unsigned int* __restrict__ out, int N)
{
    __shared__ float4 wlds4[80];
    __shared__ float4 f1t[4][CHUNK * 9];
    __shared__ int    segt[4][CHUNK];
    float* wl = (float*)wlds4;
    for (int m = threadIdx.x; m < NIN * F1; m += 256) wl[m] = ws[WS_W1P + m];
    if (threadIdx.x < F1) wl[NIN * F1 + threadIdx.x] = ws[WS_SH1 + threadIdx.x];

    const int lane = threadIdx.x & 63, wv = threadIdx.x >> 6;
    const float sc2j = ws[WS_SC2 + lane];
    const float sh2j = ws[WS_SH2 + lane];
    float w2col[F1];
#pragma unroll
    for (int k = 0; k < F1; ++k) w2col[k] = w2[k * F2 + lane] * sc2j;  // fold BN2
    const float b2j = fmaf(b2[lane], sc2j, sh2j);
    __syncthreads();

    const int nchunks = (N + CHUNK - 1) / CHUNK;
    for (int c = blockIdx.x * 4 + wv; c < nchunks; c += gridDim.x * 4) {
        const int base = c * CHUNK;
        const int i = base + lane;
        if (i < N) {
            compute_f1_lds(pts + (size_t)i * NIN, wl, &f1t[wv][lane * 9]);
            segt[wv][lane] = idx[i];
        }
        const int n = min(CHUNK, N - base);
        int p = 0;
        for (; p + 1 < n; p += 2) {
            const float4* r0 = &f1t[wv][p * 9];
            const float4* r1 = &f1t[wv][(p + 1) * 9];
            float h0 = b2j, h1 = b2j;
#pragma unroll
            for (int k4 = 0; k4 < 8; ++k4) {
                const float4 a = r0[k4], b = r1[k4];
                h0 = fmaf(a.x, w2col[4*k4+0], h0); h1 = fmaf(b.x, w2col[4*k4+0], h1);
                h0 = fmaf(a.y, w2col[4*k4+1], h0); h1 = fmaf(b.y, w2col[4*k4+1], h1);
                h0 = fmaf(a.z, w2col[4*k4+2], h0); h1 = fmaf(b.z, w2col[4*k4+2], h1);
                h0 = fmaf(a.w, w2col[4*k4+3], h0); h1 = fmaf(b.w, w2col[4*k4+3], h1);
            }
            const int s0 = segt[wv][p], s1 = segt[wv][p + 1];
            if (h0 > 0.f) atomicMax(out + (size_t)s0 * F2 + lane, __float_as_uint(h0));
            if (h1 > 0.f) atomicMax(out + (size_t)s1 * F2 + lane, __float_as_uint(h1));
        }
        if (p < n) {
            const float4* r0 = &f1t[wv][p * 9];
            float h0 = b2j;
#pragma unroll
            for (int k4 = 0; k4 < 8; ++k4) {
                const float4 a = r0[k4];
                h0 = fmaf(a.x, w2col[4*k4+0], h0);
                h0 = fmaf(a.y, w2col[4*k4+1], h0);
                h0 = fmaf(a.z, w2col[4*k4+2], h0);
                h0 = fmaf(a.w, w2col[4*k4+3], h0);
            }
            const int s0 = segt[wv][p];
            if (h0 > 0.f) atomicMax(out + (size_t)s0 * F2 + lane, __float_as_uint(h0));
        }
    }
}

extern "C" void kernel_launch(void* const* d_in, const int* in_sizes, int n_in,
                              void* d_out, int out_size, void* d_ws, size_t ws_size,
                              hipStream_t stream)
{
    const float* pts = (const float*)d_in[0];
    const int*   idx = (const int*)d_in[1];
    const float* w1  = (const float*)d_in[3];
    const float* b1  = (const float*)d_in[4];
    const float* g1  = (const float*)d_in[5];
    const float* be1 = (const float*)d_in[6];
    const float* w2  = (const float*)d_in[7];
    const float* b2  = (const float*)d_in[8];
    const float* g2  = (const float*)d_in[9];
    const float* be2 = (const float*)d_in[10];

    float* ws = (float*)d_ws;
    const int N = in_sizes[0] / NIN;
    const float invN = 1.0f / (float)N;

    hipMemsetAsync(ws, 0, 192 * sizeof(float), stream);
    hipMemsetAsync(d_out, 0, (size_t)out_size * sizeof(float), stream);

    moments_kernel<<<1024, 256, 0, stream>>>(pts, ws, N);
    finalize1_kernel<<<1, 320, 0, stream>>>(w1, b1, g1, be1, ws, invN);
    stats2_kernel<<<1024, 256, 0, stream>>>(pts, w2, b2, ws, N);
    finalize2_kernel<<<1, 64, 0, stream>>>(g2, be2, ws, invN);
    scatter_kernel<<<1024, 256, 0, stream>>>(pts, idx, w2, b2, ws,
                                             (unsigned int*)d_out, N);
}

// Round 4
// 523.913 us; speedup vs baseline: 2.2752x; 2.2752x over previous
//
#include <hip/hip_runtime.h>

#define EPS 1e-5f
#define NIN 9
#define F1 32
#define F2 64
#define NMOM 45
#define CHUNK 64
#define ROWB 80   // bytes per bf16 f1 row in LDS: 64B data + 16B pad (80 = 5*16, keeps b128 alignment, spreads banks)

// ws float offsets
#define WS_S    0     // 9   sum x
#define WS_M    16    // 45  sum xx^T upper-tri
#define WS_S2   64    // 64  sum h2
#define WS_SS2  128   // 64  sum h2^2
#define WS_SC1  192   // 32  scale1
#define WS_SH1  224   // 32  folded shift1' = be1 - mean*scale1
#define WS_W1P  256   // 288 w1 * scale1
#define WS_SC2  544   // 64
#define WS_SH2  608   // 64

typedef __attribute__((ext_vector_type(8))) short bf16x8;
typedef __attribute__((ext_vector_type(4))) float f32x4;

__device__ __forceinline__ unsigned int f2bf(float f) {
    unsigned int u = __float_as_uint(f);
    return (u + 0x7fffu + ((u >> 16) & 1u)) >> 16;   // RNE
}
__device__ __forceinline__ unsigned int pack2(float lo, float hi) {
    return f2bf(lo) | (f2bf(hi) << 16);
}

// ---------------- Pass A: x moments ----------------
__global__ __launch_bounds__(256, 4) void moments_kernel(
    const float* __restrict__ pts, float* __restrict__ ws, int N)
{
    float S[NIN], M[NMOM];
#pragma unroll
    for (int k = 0; k < NIN; ++k) S[k] = 0.f;
#pragma unroll
    for (int m = 0; m < NMOM; ++m) M[m] = 0.f;

    const int stride = gridDim.x * blockDim.x;
    for (int i = blockIdx.x * blockDim.x + threadIdx.x; i < N; i += stride) {
        const float* p = pts + (size_t)i * NIN;
        float x[NIN];
#pragma unroll
        for (int k = 0; k < NIN; ++k) x[k] = p[k];
        int m = 0;
#pragma unroll
        for (int k = 0; k < NIN; ++k) {
            S[k] += x[k];
#pragma unroll
            for (int l = k; l < NIN; ++l) { M[m] = fmaf(x[k], x[l], M[m]); ++m; }
        }
    }
#pragma unroll
    for (int off = 32; off > 0; off >>= 1) {
#pragma unroll
        for (int k = 0; k < NIN; ++k) S[k] += __shfl_xor(S[k], off, 64);
#pragma unroll
        for (int m = 0; m < NMOM; ++m) M[m] += __shfl_xor(M[m], off, 64);
    }
    __shared__ float red[64];
    if (threadIdx.x < 64) red[threadIdx.x] = 0.f;
    __syncthreads();
    if ((threadIdx.x & 63) == 0) {
#pragma unroll
        for (int k = 0; k < NIN; ++k) atomicAdd(&red[WS_S + k], S[k]);
#pragma unroll
        for (int m = 0; m < NMOM; ++m) atomicAdd(&red[WS_M + m], M[m]);
    }
    __syncthreads();
    if (threadIdx.x < 64) atomicAdd(&ws[threadIdx.x], red[threadIdx.x]);
}

// ---------------- finalize1: BN1 params from moments + fold weights ----------------
__global__ void finalize1_kernel(
    const float* __restrict__ w1, const float* __restrict__ b1,
    const float* __restrict__ g1, const float* __restrict__ be1,
    float* __restrict__ ws, float invN)
{
    __shared__ float sc1s[F1];
    const int j = threadIdx.x;
    if (j < F1) {
        float W[NIN];
        float P = 0.f;
#pragma unroll
        for (int k = 0; k < NIN; ++k) {
            W[k] = w1[k * F1 + j];
            P = fmaf(ws[WS_S + k], W[k], P);
        }
        float Q = 0.f;
        int m = 0;
#pragma unroll
        for (int k = 0; k < NIN; ++k) {
            Q = fmaf(ws[WS_M + m], W[k] * W[k], Q); ++m;
#pragma unroll
            for (int l = k + 1; l < NIN; ++l) {
                Q = fmaf(2.f * ws[WS_M + m], W[k] * W[l], Q); ++m;
            }
        }
        const float b = b1[j];
        const float mean = fmaf(P, invN, b);
        const float Eh2 = fmaf(fmaf(2.f * b, P, Q), invN, b * b);
        const float var = Eh2 - mean * mean;
        const float sc = g1[j] * rsqrtf(var + EPS);
        ws[WS_SC1 + j] = sc;
        ws[WS_SH1 + j] = be1[j] - mean * sc;
        sc1s[j] = sc;
    }
    __syncthreads();
    for (int m = threadIdx.x; m < NIN * F1; m += blockDim.x)
        ws[WS_W1P + m] = w1[m] * sc1s[m & (F1 - 1)];
}

// padf = number of zero-padded points in the last chunk; their D=0 rows
// contribute b2 / b2^2 to the sums — subtract analytically.
__global__ void finalize2_kernel(
    const float* __restrict__ g2, const float* __restrict__ be2,
    const float* __restrict__ b2, float* __restrict__ ws, float invN, float padf)
{
    const int j = threadIdx.x;
    if (j < F2) {
        const float b = b2[j];
        const float S  = ws[WS_S2 + j]  - padf * b;
        const float SS = ws[WS_SS2 + j] - padf * b * b;
        const float mean = S * invN;
        const float var  = SS * invN - mean * mean;
        const float sc   = g2[j] * rsqrtf(var + EPS);
        ws[WS_SC2 + j] = sc;
        ws[WS_SH2 + j] = be2[j] - mean * sc;
    }
}

// f1 (fp32, uniform scalar weights) -> packed bf16 row (32 bf16 = 4 uint4)
__device__ __forceinline__ void f1_row_bf16(
    const float* __restrict__ p, const float* __restrict__ wl,
    const float* __restrict__ sh1, unsigned int* __restrict__ pk /*[16]*/)
{
    float x[NIN];
#pragma unroll
    for (int k = 0; k < NIN; ++k) x[k] = p[k];
#pragma unroll
    for (int fc = 0; fc < 4; ++fc) {
        float h[8];
#pragma unroll
        for (int jj = 0; jj < 8; ++jj) h[jj] = sh1[fc * 8 + jj];
#pragma unroll
        for (int k = 0; k < NIN; ++k) {
            const float xv = x[k];
#pragma unroll
            for (int jj = 0; jj < 8; ++jj)
                h[jj] = fmaf(xv, wl[k * F1 + fc * 8 + jj], h[jj]);
        }
#pragma unroll
        for (int jj = 0; jj < 4; ++jj)
            pk[fc * 4 + jj] = pack2(fmaxf(h[2 * jj], 0.f), fmaxf(h[2 * jj + 1], 0.f));
    }
}

// ---------------- Pass B: h2 stats via MFMA ----------------
__global__ __launch_bounds__(256, 3) void stats2_kernel(
    const float* __restrict__ pts, const float* __restrict__ w2,
    const float* __restrict__ b2, float* __restrict__ ws, int N)
{
    __shared__ __align__(16) unsigned char f1raw[4][CHUNK * ROWB];
    __shared__ float red[2 * F2];

    const int lane = threadIdx.x & 63, wv = threadIdx.x >> 6;
    const int quad = lane >> 4, m16 = lane & 15;

    // B-frag[nt][j] = bf16(w2[k = quad*8+j][n = nt*16+m16])
    bf16x8 bfr[4];
#pragma unroll
    for (int nt = 0; nt < 4; ++nt)
#pragma unroll
        for (int j = 0; j < 8; ++j)
            bfr[nt][j] = (short)f2bf(w2[(quad * 8 + j) * F2 + nt * 16 + m16]);
    float b2f[4];
#pragma unroll
    for (int nt = 0; nt < 4; ++nt) b2f[nt] = b2[nt * 16 + m16];

    const float* wl  = ws + WS_W1P;
    const float* sh1 = ws + WS_SH1;
    const f32x4 zero = {0.f, 0.f, 0.f, 0.f};

    float s[4] = {0.f, 0.f, 0.f, 0.f}, ss[4] = {0.f, 0.f, 0.f, 0.f};

    unsigned char* myf1 = f1raw[wv];
    const int nchunks = (N + CHUNK - 1) / CHUNK;
    for (int c = blockIdx.x * 4 + wv; c < nchunks; c += gridDim.x * 4) {
        const int i = c * CHUNK + lane;
        unsigned int pk[16];
        if (i < N) {
            f1_row_bf16(pts + (size_t)i * NIN, wl, sh1, pk);
        } else {
#pragma unroll
            for (int q = 0; q < 16; ++q) pk[q] = 0u;
        }
        uint4* wrow = (uint4*)(myf1 + lane * ROWB);
#pragma unroll
        for (int cidx = 0; cidx < 4; ++cidx)
            wrow[cidx] = make_uint4(pk[4*cidx+0], pk[4*cidx+1], pk[4*cidx+2], pk[4*cidx+3]);

        // A-frag[mt][j] = f1[row = mt*16+m16][k = quad*8+j] (same-wave LDS, lgkm-ordered)
        bf16x8 afr[4];
#pragma unroll
        for (int mt = 0; mt < 4; ++mt)
            afr[mt] = *(const bf16x8*)(myf1 + (mt * 16 + m16) * ROWB + quad * 16);

#pragma unroll
        for (int mt = 0; mt < 4; ++mt) {
#pragma unroll
            for (int nt = 0; nt < 4; ++nt) {
                f32x4 d = __builtin_amdgcn_mfma_f32_16x16x32_bf16(afr[mt], bfr[nt], zero, 0, 0, 0);
#pragma unroll
                for (int r = 0; r < 4; ++r) {
                    const float v = d[r] + b2f[nt];
                    s[nt] += v;
                    ss[nt] = fmaf(v, v, ss[nt]);
                }
            }
        }
    }

    // reduce over the 4 quads (feature j = nt*16+m16 lives in all quads)
#pragma unroll
    for (int off = 16; off < 64; off <<= 1)
#pragma unroll
        for (int nt = 0; nt < 4; ++nt) {
            s[nt]  += __shfl_xor(s[nt], off, 64);
            ss[nt] += __shfl_xor(ss[nt], off, 64);
        }
    if (threadIdx.x < 2 * F2) red[threadIdx.x] = 0.f;
    __syncthreads();
    if (quad == 0) {
#pragma unroll
        for (int nt = 0; nt < 4; ++nt) {
            atomicAdd(&red[nt * 16 + m16], s[nt]);
            atomicAdd(&red[F2 + nt * 16 + m16], ss[nt]);
        }
    }
    __syncthreads();
    if (threadIdx.x < F2) {
        atomicAdd(&ws[WS_S2 + threadIdx.x],  red[threadIdx.x]);
        atomicAdd(&ws[WS_SS2 + threadIdx.x], red[F2 + threadIdx.x]);
    }
}

// ---------------- Pass C: feat2 via MFMA + segment atomicMax ----------------
__global__ __launch_bounds__(256, 3) void scatter_kernel(
    const float* __restrict__ pts, const int* __restrict__ idx,
    const float* __restrict__ w2, const float* __restrict__ b2,
    const float* __restrict__ ws, unsigned int* __restrict__ out, int N)
{
    __shared__ __align__(16) unsigned char f1raw[4][CHUNK * ROWB];
    __shared__ int segt[4][CHUNK];

    const int lane = threadIdx.x & 63, wv = threadIdx.x >> 6;
    const int quad = lane >> 4, m16 = lane & 15;

    bf16x8 bfr[4];
#pragma unroll
    for (int nt = 0; nt < 4; ++nt)
#pragma unroll
        for (int j = 0; j < 8; ++j)
            bfr[nt][j] = (short)f2bf(w2[(quad * 8 + j) * F2 + nt * 16 + m16]);

    // fold BN2: feat2 = D*sc2 + (b2*sc2 + sh2)
    float sc2f[4], shb[4];
#pragma unroll
    for (int nt = 0; nt < 4; ++nt) {
        const int f = nt * 16 + m16;
        sc2f[nt] = ws[WS_SC2 + f];
        shb[nt]  = fmaf(b2[f], sc2f[nt], ws[WS_SH2 + f]);
    }

    const float* wl  = ws + WS_W1P;
    const float* sh1 = ws + WS_SH1;
    const f32x4 zero = {0.f, 0.f, 0.f, 0.f};

    unsigned char* myf1 = f1raw[wv];
    int* myseg = segt[wv];
    const int nchunks = (N + CHUNK - 1) / CHUNK;
    for (int c = blockIdx.x * 4 + wv; c < nchunks; c += gridDim.x * 4) {
        const int i = c * CHUNK + lane;
        unsigned int pk[16];
        int sg = -1;
        if (i < N) {
            f1_row_bf16(pts + (size_t)i * NIN, wl, sh1, pk);
            sg = idx[i];
        } else {
#pragma unroll
            for (int q = 0; q < 16; ++q) pk[q] = 0u;
        }
        uint4* wrow = (uint4*)(myf1 + lane * ROWB);
#pragma unroll
        for (int cidx = 0; cidx < 4; ++cidx)
            wrow[cidx] = make_uint4(pk[4*cidx+0], pk[4*cidx+1], pk[4*cidx+2], pk[4*cidx+3]);
        myseg[lane] = sg;

        bf16x8 afr[4];
#pragma unroll
        for (int mt = 0; mt < 4; ++mt)
            afr[mt] = *(const bf16x8*)(myf1 + (mt * 16 + m16) * ROWB + quad * 16);

#pragma unroll
        for (int mt = 0; mt < 4; ++mt) {
            f32x4 d[4];
#pragma unroll
            for (int nt = 0; nt < 4; ++nt)
                d[nt] = __builtin_amdgcn_mfma_f32_16x16x32_bf16(afr[mt], bfr[nt], zero, 0, 0, 0);
#pragma unroll
            for (int r = 0; r < 4; ++r) {
                // D row = point mt*16 + quad*4 + r; col = feature nt*16 + m16
                const int sgp = myseg[mt * 16 + quad * 4 + r];
                if (sgp >= 0) {
                    unsigned int* outp = out + (size_t)sgp * F2 + m16;
#pragma unroll
                    for (int nt = 0; nt < 4; ++nt) {
                        const float v = fmaf(d[nt][r], sc2f[nt], shb[nt]);
                        if (v > 0.f)
                            atomicMax(outp + nt * 16, __float_as_uint(v));
                    }
                }
            }
        }
    }
}

extern "C" void kernel_launch(void* const* d_in, const int* in_sizes, int n_in,
                              void* d_out, int out_size, void* d_ws, size_t ws_size,
                              hipStream_t stream)
{
    const float* pts = (const float*)d_in[0];
    const int*   idx = (const int*)d_in[1];
    const float* w1  = (const float*)d_in[3];
    const float* b1  = (const float*)d_in[4];
    const float* g1  = (const float*)d_in[5];
    const float* be1 = (const float*)d_in[6];
    const float* w2  = (const float*)d_in[7];
    const float* b2  = (const float*)d_in[8];
    const float* g2  = (const float*)d_in[9];
    const float* be2 = (const float*)d_in[10];

    float* ws = (float*)d_ws;
    const int N = in_sizes[0] / NIN;
    const float invN = 1.0f / (float)N;
    const float padf = (float)((CHUNK - (N % CHUNK)) % CHUNK);

    hipMemsetAsync(ws, 0, 192 * sizeof(float), stream);
    hipMemsetAsync(d_out, 0, (size_t)out_size * sizeof(float), stream);

    moments_kernel<<<1024, 256, 0, stream>>>(pts, ws, N);
    finalize1_kernel<<<1, 320, 0, stream>>>(w1, b1, g1, be1, ws, invN);
    stats2_kernel<<<1024, 256, 0, stream>>>(pts, w2, b2, ws, N);
    finalize2_kernel<<<1, 64, 0, stream>>>(g2, be2, b2, ws, invN, padf);
    scatter_kernel<<<1024, 256, 0, stream>>>(pts, idx, w2, b2, ws,
                                             (unsigned int*)d_out, N);
}

// Round 5
// 503.491 us; speedup vs baseline: 2.3674x; 1.0406x over previous
//
#include <hip/hip_runtime.h>

#define EPS 1e-5f
#define NIN 9
#define F1 32
#define F2 64
#define NMOM 45
#define CHUNK 64
#define ROWB 80    // bytes per bf16 f1 row in LDS
#define F2STRIDE 68  // fp32 f2 window row stride (272B: quads land 16 banks apart -> 2-way, free)

// ws float offsets (params region, < 1024 floats)
#define WS_S    0
#define WS_M    16
#define WS_S2   64
#define WS_SS2  128
#define WS_SC1  192
#define WS_SH1  224
#define WS_W1P  256
#define WS_SC2  544
#define WS_SH2  608

typedef __attribute__((ext_vector_type(8))) short bf16x8;
typedef __attribute__((ext_vector_type(4))) float f32x4;

__device__ __forceinline__ unsigned int f2bf(float f) {
    unsigned int u = __float_as_uint(f);
    return (u + 0x7fffu + ((u >> 16) & 1u)) >> 16;   // RNE
}
__device__ __forceinline__ unsigned int pack2(float lo, float hi) {
    return f2bf(lo) | (f2bf(hi) << 16);
}

// ---------------- Pass A: x moments + segment histogram ----------------
__global__ __launch_bounds__(256, 4) void moments_kernel(
    const float* __restrict__ pts, const int* __restrict__ idx,
    float* __restrict__ ws, int* __restrict__ hist, int N)
{
    float S[NIN], M[NMOM];
#pragma unroll
    for (int k = 0; k < NIN; ++k) S[k] = 0.f;
#pragma unroll
    for (int m = 0; m < NMOM; ++m) M[m] = 0.f;

    const int stride = gridDim.x * blockDim.x;
    for (int i = blockIdx.x * blockDim.x + threadIdx.x; i < N; i += stride) {
        const float* p = pts + (size_t)i * NIN;
        atomicAdd(&hist[idx[i]], 1);
        float x[NIN];
#pragma unroll
        for (int k = 0; k < NIN; ++k) x[k] = p[k];
        int m = 0;
#pragma unroll
        for (int k = 0; k < NIN; ++k) {
            S[k] += x[k];
#pragma unroll
            for (int l = k; l < NIN; ++l) { M[m] = fmaf(x[k], x[l], M[m]); ++m; }
        }
    }
#pragma unroll
    for (int off = 32; off > 0; off >>= 1) {
#pragma unroll
        for (int k = 0; k < NIN; ++k) S[k] += __shfl_xor(S[k], off, 64);
#pragma unroll
        for (int m = 0; m < NMOM; ++m) M[m] += __shfl_xor(M[m], off, 64);
    }
    __shared__ float red[64];
    if (threadIdx.x < 64) red[threadIdx.x] = 0.f;
    __syncthreads();
    if ((threadIdx.x & 63) == 0) {
#pragma unroll
        for (int k = 0; k < NIN; ++k) atomicAdd(&red[WS_S + k], S[k]);
#pragma unroll
        for (int m = 0; m < NMOM; ++m) atomicAdd(&red[WS_M + m], M[m]);
    }
    __syncthreads();
    if (threadIdx.x < 64) atomicAdd(&ws[threadIdx.x], red[threadIdx.x]);
}

// ---------------- counting-sort scan kernels ----------------
__global__ void scan1_kernel(const int* __restrict__ hist, int* __restrict__ cursor,
                             int* __restrict__ bsum, int nseg)
{
    __shared__ int tmp[256];
    const int tid = threadIdx.x;
    const int i = blockIdx.x * 256 + tid;
    const int v = (i < nseg) ? hist[i] : 0;
    tmp[tid] = v;
    __syncthreads();
#pragma unroll
    for (int off = 1; off < 256; off <<= 1) {
        int t = (tid >= off) ? tmp[tid - off] : 0;
        __syncthreads();
        tmp[tid] += t;
        __syncthreads();
    }
    if (i < nseg) cursor[i] = tmp[tid] - v;      // exclusive within block
    if (tid == 255) bsum[blockIdx.x] = tmp[255];
}

__global__ void scan2_kernel(int* __restrict__ bsum, int nb)
{
    const int lane = threadIdx.x;   // 64 threads, 1 block
    int carry = 0;
    for (int base = 0; base < nb; base += 64) {
        const int i = base + lane;
        int v = (i < nb) ? bsum[i] : 0;
        const int orig = v;
#pragma unroll
        for (int off = 1; off < 64; off <<= 1) {
            int t = __shfl_up(v, off, 64);
            if (lane >= off) v += t;
        }
        if (i < nb) bsum[i] = v - orig + carry;
        carry += __shfl(v, 63, 64);
    }
}

__global__ void scan3_kernel(int* __restrict__ cursor, const int* __restrict__ bsum, int nseg)
{
    const int i = blockIdx.x * 256 + threadIdx.x;
    if (i < nseg) cursor[i] += bsum[i >> 8];
}

__global__ __launch_bounds__(256, 4) void placement_kernel(
    const int* __restrict__ idx, int* __restrict__ cursor,
    int* __restrict__ sidx, int* __restrict__ sseg, int N)
{
    const int stride = gridDim.x * blockDim.x;
    for (int i = blockIdx.x * blockDim.x + threadIdx.x; i < N; i += stride) {
        const int sg = idx[i];
        const int pos = atomicAdd(&cursor[sg], 1);
        sidx[pos] = i;
        sseg[pos] = sg;
    }
}

// ---------------- finalize kernels ----------------
__global__ void finalize1_kernel(
    const float* __restrict__ w1, const float* __restrict__ b1,
    const float* __restrict__ g1, const float* __restrict__ be1,
    float* __restrict__ ws, float invN)
{
    __shared__ float sc1s[F1];
    const int j = threadIdx.x;
    if (j < F1) {
        float W[NIN];
        float P = 0.f;
#pragma unroll
        for (int k = 0; k < NIN; ++k) {
            W[k] = w1[k * F1 + j];
            P = fmaf(ws[WS_S + k], W[k], P);
        }
        float Q = 0.f;
        int m = 0;
#pragma unroll
        for (int k = 0; k < NIN; ++k) {
            Q = fmaf(ws[WS_M + m], W[k] * W[k], Q); ++m;
#pragma unroll
            for (int l = k + 1; l < NIN; ++l) {
                Q = fmaf(2.f * ws[WS_M + m], W[k] * W[l], Q); ++m;
            }
        }
        const float b = b1[j];
        const float mean = fmaf(P, invN, b);
        const float Eh2 = fmaf(fmaf(2.f * b, P, Q), invN, b * b);
        const float var = Eh2 - mean * mean;
        const float sc = g1[j] * rsqrtf(var + EPS);
        ws[WS_SC1 + j] = sc;
        ws[WS_SH1 + j] = be1[j] - mean * sc;
        sc1s[j] = sc;
    }
    __syncthreads();
    for (int m = threadIdx.x; m < NIN * F1; m += blockDim.x)
        ws[WS_W1P + m] = w1[m] * sc1s[m & (F1 - 1)];
}

__global__ void finalize2_kernel(
    const float* __restrict__ g2, const float* __restrict__ be2,
    const float* __restrict__ b2, float* __restrict__ ws, float invN, float padf)
{
    const int j = threadIdx.x;
    if (j < F2) {
        const float b = b2[j];
        const float S  = ws[WS_S2 + j]  - padf * b;
        const float SS = ws[WS_SS2 + j] - padf * b * b;
        const float mean = S * invN;
        const float var  = SS * invN - mean * mean;
        const float sc   = g2[j] * rsqrtf(var + EPS);
        ws[WS_SC2 + j] = sc;
        ws[WS_SH2 + j] = be2[j] - mean * sc;
    }
}

// f1 (fp32, uniform scalar weights) -> packed bf16 row (32 bf16 = 4 uint4)
__device__ __forceinline__ void f1_row_bf16(
    const float* __restrict__ p, const float* __restrict__ wl,
    const float* __restrict__ sh1, unsigned int* __restrict__ pk /*[16]*/)
{
    float x[NIN];
#pragma unroll
    for (int k = 0; k < NIN; ++k) x[k] = p[k];
#pragma unroll
    for (int fc = 0; fc < 4; ++fc) {
        float h[8];
#pragma unroll
        for (int jj = 0; jj < 8; ++jj) h[jj] = sh1[fc * 8 + jj];
#pragma unroll
        for (int k = 0; k < NIN; ++k) {
            const float xv = x[k];
#pragma unroll
            for (int jj = 0; jj < 8; ++jj)
                h[jj] = fmaf(xv, wl[k * F1 + fc * 8 + jj], h[jj]);
        }
#pragma unroll
        for (int jj = 0; jj < 4; ++jj)
            pk[fc * 4 + jj] = pack2(fmaxf(h[2 * jj], 0.f), fmaxf(h[2 * jj + 1], 0.f));
    }
}

// ---------------- Pass B: h2 stats via MFMA (unchanged structure) ----------------
__global__ __launch_bounds__(256, 3) void stats2_kernel(
    const float* __restrict__ pts, const float* __restrict__ w2,
    const float* __restrict__ b2, float* __restrict__ ws, int N)
{
    __shared__ __align__(16) unsigned char f1raw[4][CHUNK * ROWB];
    __shared__ float red[2 * F2];

    const int lane = threadIdx.x & 63, wv = threadIdx.x >> 6;
    const int quad = lane >> 4, m16 = lane & 15;

    bf16x8 bfr[4];
#pragma unroll
    for (int nt = 0; nt < 4; ++nt)
#pragma unroll
        for (int j = 0; j < 8; ++j)
            bfr[nt][j] = (short)f2bf(w2[(quad * 8 + j) * F2 + nt * 16 + m16]);
    float b2f[4];
#pragma unroll
    for (int nt = 0; nt < 4; ++nt) b2f[nt] = b2[nt * 16 + m16];

    const float* wl  = ws + WS_W1P;
    const float* sh1 = ws + WS_SH1;
    const f32x4 zero = {0.f, 0.f, 0.f, 0.f};

    float s[4] = {0.f, 0.f, 0.f, 0.f}, ss[4] = {0.f, 0.f, 0.f, 0.f};

    unsigned char* myf1 = f1raw[wv];
    const int nchunks = (N + CHUNK - 1) / CHUNK;
    for (int c = blockIdx.x * 4 + wv; c < nchunks; c += gridDim.x * 4) {
        const int i = c * CHUNK + lane;
        unsigned int pk[16];
        if (i < N) {
            f1_row_bf16(pts + (size_t)i * NIN, wl, sh1, pk);
        } else {
#pragma unroll
            for (int q = 0; q < 16; ++q) pk[q] = 0u;
        }
        uint4* wrow = (uint4*)(myf1 + lane * ROWB);
#pragma unroll
        for (int cidx = 0; cidx < 4; ++cidx)
            wrow[cidx] = make_uint4(pk[4*cidx+0], pk[4*cidx+1], pk[4*cidx+2], pk[4*cidx+3]);

        bf16x8 afr[4];
#pragma unroll
        for (int mt = 0; mt < 4; ++mt)
            afr[mt] = *(const bf16x8*)(myf1 + (mt * 16 + m16) * ROWB + quad * 16);

#pragma unroll
        for (int mt = 0; mt < 4; ++mt) {
#pragma unroll
            for (int nt = 0; nt < 4; ++nt) {
                f32x4 d = __builtin_amdgcn_mfma_f32_16x16x32_bf16(afr[mt], bfr[nt], zero, 0, 0, 0);
#pragma unroll
                for (int r = 0; r < 4; ++r) {
                    const float v = d[r] + b2f[nt];
                    s[nt] += v;
                    ss[nt] = fmaf(v, v, ss[nt]);
                }
            }
        }
    }

#pragma unroll
    for (int off = 16; off < 64; off <<= 1)
#pragma unroll
        for (int nt = 0; nt < 4; ++nt) {
            s[nt]  += __shfl_xor(s[nt], off, 64);
            ss[nt] += __shfl_xor(ss[nt], off, 64);
        }
    if (threadIdx.x < 2 * F2) red[threadIdx.x] = 0.f;
    __syncthreads();
    if (quad == 0) {
#pragma unroll
        for (int nt = 0; nt < 4; ++nt) {
            atomicAdd(&red[nt * 16 + m16], s[nt]);
            atomicAdd(&red[F2 + nt * 16 + m16], ss[nt]);
        }
    }
    __syncthreads();
    if (threadIdx.x < F2) {
        atomicAdd(&ws[WS_S2 + threadIdx.x],  red[threadIdx.x]);
        atomicAdd(&ws[WS_SS2 + threadIdx.x], red[F2 + threadIdx.x]);
    }
}

// ---------------- Pass C: sorted points, MFMA + run-aggregated atomicMax ----------------
__global__ __launch_bounds__(256, 3) void scatter_kernel(
    const float* __restrict__ pts, const int* __restrict__ sidx,
    const int* __restrict__ sseg, const float* __restrict__ w2,
    const float* __restrict__ b2, const float* __restrict__ ws,
    unsigned int* __restrict__ out, int N)
{
    __shared__ __align__(16) unsigned char f1raw[4][CHUNK * ROWB];
    __shared__ float f2win[4][16 * F2STRIDE];
    __shared__ int segt[4][CHUNK];

    const int lane = threadIdx.x & 63, wv = threadIdx.x >> 6;
    const int quad = lane >> 4, m16 = lane & 15;

    bf16x8 bfr[4];
#pragma unroll
    for (int nt = 0; nt < 4; ++nt)
#pragma unroll
        for (int j = 0; j < 8; ++j)
            bfr[nt][j] = (short)f2bf(w2[(quad * 8 + j) * F2 + nt * 16 + m16]);

    float sc2f[4], shb[4];
#pragma unroll
    for (int nt = 0; nt < 4; ++nt) {
        const int f = nt * 16 + m16;
        sc2f[nt] = ws[WS_SC2 + f];
        shb[nt]  = fmaf(b2[f], sc2f[nt], ws[WS_SH2 + f]);
    }

    const float* wl  = ws + WS_W1P;
    const float* sh1 = ws + WS_SH1;
    const f32x4 zero = {0.f, 0.f, 0.f, 0.f};

    unsigned char* myf1 = f1raw[wv];
    float* myf2 = f2win[wv];
    int* myseg = segt[wv];
    const int nchunks = (N + CHUNK - 1) / CHUNK;
    for (int c = blockIdx.x * 4 + wv; c < nchunks; c += gridDim.x * 4) {
        const int sp = c * CHUNK + lane;
        unsigned int pk[16];
        int sg = -1;
        if (sp < N) {
            const int gi = sidx[sp];
            f1_row_bf16(pts + (size_t)gi * NIN, wl, sh1, pk);
            sg = sseg[sp];
        } else {
#pragma unroll
            for (int q = 0; q < 16; ++q) pk[q] = 0u;
        }
        uint4* wrow = (uint4*)(myf1 + lane * ROWB);
#pragma unroll
        for (int cidx = 0; cidx < 4; ++cidx)
            wrow[cidx] = make_uint4(pk[4*cidx+0], pk[4*cidx+1], pk[4*cidx+2], pk[4*cidx+3]);
        myseg[lane] = sg;

        bf16x8 afr[4];
#pragma unroll
        for (int mt = 0; mt < 4; ++mt)
            afr[mt] = *(const bf16x8*)(myf1 + (mt * 16 + m16) * ROWB + quad * 16);

        int cur = -1;
        float acc = -3.4e38f;
#pragma unroll
        for (int mt = 0; mt < 4; ++mt) {
            f32x4 d[4];
#pragma unroll
            for (int nt = 0; nt < 4; ++nt)
                d[nt] = __builtin_amdgcn_mfma_f32_16x16x32_bf16(afr[mt], bfr[nt], zero, 0, 0, 0);
            // stage D (BN2-folded) into the per-wave fp32 window: row = quad*4+r, col = nt*16+m16
#pragma unroll
            for (int r = 0; r < 4; ++r)
#pragma unroll
                for (int nt = 0; nt < 4; ++nt)
                    myf2[(quad * 4 + r) * F2STRIDE + nt * 16 + m16] =
                        fmaf(d[nt][r], sc2f[nt], shb[nt]);
            // consume: lane = feature, segmented max over the 16 sorted rows
            for (int p = 0; p < 16; ++p) {
                const int sg2 = myseg[mt * 16 + p];          // wave-uniform broadcast
                const float v = myf2[p * F2STRIDE + lane];
                if (sg2 != cur) {
                    if (cur >= 0 && acc > 0.f)
                        atomicMax(out + (size_t)cur * F2 + lane, __float_as_uint(acc));
                    cur = sg2;
                    acc = v;
                } else {
                    acc = fmaxf(acc, v);
                }
            }
        }
        if (cur >= 0 && acc > 0.f)
            atomicMax(out + (size_t)cur * F2 + lane, __float_as_uint(acc));
    }
}

extern "C" void kernel_launch(void* const* d_in, const int* in_sizes, int n_in,
                              void* d_out, int out_size, void* d_ws, size_t ws_size,
                              hipStream_t stream)
{
    const float* pts = (const float*)d_in[0];
    const int*   idx = (const int*)d_in[1];
    const float* w1  = (const float*)d_in[3];
    const float* b1  = (const float*)d_in[4];
    const float* g1  = (const float*)d_in[5];
    const float* be1 = (const float*)d_in[6];
    const float* w2  = (const float*)d_in[7];
    const float* b2  = (const float*)d_in[8];
    const float* g2  = (const float*)d_in[9];
    const float* be2 = (const float*)d_in[10];

    float* ws = (float*)d_ws;
    const int N = in_sizes[0] / NIN;
    const int nseg = out_size / F2;
    const float invN = 1.0f / (float)N;
    const float padf = (float)((CHUNK - (N % CHUNK)) % CHUNK);

    // int scratch layout after the 1024-float param region
    int* hist   = (int*)d_ws + 1024;
    int* bsum   = hist + nseg;
    int* cursor = bsum + 1024;
    int* sidx   = cursor + nseg;
    int* sseg   = sidx + N;
    const int nb1 = (nseg + 255) / 256;

    hipMemsetAsync(ws, 0, 192 * sizeof(float), stream);
    hipMemsetAsync(hist, 0, (size_t)nseg * sizeof(int), stream);
    hipMemsetAsync(d_out, 0, (size_t)out_size * sizeof(float), stream);

    moments_kernel<<<1024, 256, 0, stream>>>(pts, idx, ws, hist, N);
    finalize1_kernel<<<1, 320, 0, stream>>>(w1, b1, g1, be1, ws, invN);

    scan1_kernel<<<nb1, 256, 0, stream>>>(hist, cursor, bsum, nseg);
    scan2_kernel<<<1, 64, 0, stream>>>(bsum, nb1);
    scan3_kernel<<<nb1, 256, 0, stream>>>(cursor, bsum, nseg);
    placement_kernel<<<1024, 256, 0, stream>>>(idx, cursor, sidx, sseg, N);

    stats2_kernel<<<1024, 256, 0, stream>>>(pts, w2, b2, ws, N);
    finalize2_kernel<<<1, 64, 0, stream>>>(g2, be2, b2, ws, invN, padf);
    scatter_kernel<<<1024, 256, 0, stream>>>(pts, sidx, sseg, w2, b2, ws,
                                             (unsigned int*)d_out, N);
}

// Round 6
// 353.864 us; speedup vs baseline: 3.3685x; 1.4228x over previous
//
#include <hip/hip_runtime.h>

#define EPS 1e-5f
#define NIN 9
#define F1 32
#define F2 64
#define NMOM 45
#define CHUNK 64
#define ROWB 80      // bytes per bf16 f1 row in LDS
#define F2STRIDE 68  // fp32 f2 window row stride
#define SHIFT 7      // coarse bucket = seg >> 7 (128 segs/bucket)
#define BTILE 8192   // points per binning workgroup
#define FCAP 4096    // max points per coarse bucket handled by finesort

// ws float offsets (params region, < 1024 floats)
#define WS_S    0
#define WS_M    16
#define WS_S2   64
#define WS_SS2  128
#define WS_SC1  192
#define WS_SH1  224
#define WS_W1P  256
#define WS_SC2  544
#define WS_SH2  608

typedef __attribute__((ext_vector_type(8))) short bf16x8;
typedef __attribute__((ext_vector_type(4))) float f32x4;

__device__ __forceinline__ unsigned int f2bf(float f) {
    unsigned int u = __float_as_uint(f);
    return (u + 0x7fffu + ((u >> 16) & 1u)) >> 16;   // RNE
}
__device__ __forceinline__ unsigned int pack2(float lo, float hi) {
    return f2bf(lo) | (f2bf(hi) << 16);
}

// ---------------- Pass A: x moments + coarse segment histogram ----------------
__global__ __launch_bounds__(256, 4) void moments_kernel(
    const float* __restrict__ pts, const int* __restrict__ idx,
    float* __restrict__ ws, int* __restrict__ histc, int N, int nb)
{
    __shared__ int lhist[1024];
    __shared__ float red[64];
    for (int t = threadIdx.x; t < nb; t += 256) lhist[t] = 0;

    float S[NIN], M[NMOM];
#pragma unroll
    for (int k = 0; k < NIN; ++k) S[k] = 0.f;
#pragma unroll
    for (int m = 0; m < NMOM; ++m) M[m] = 0.f;
    __syncthreads();

    const int stride = gridDim.x * blockDim.x;
    for (int i = blockIdx.x * blockDim.x + threadIdx.x; i < N; i += stride) {
        const float* p = pts + (size_t)i * NIN;
        atomicAdd(&lhist[idx[i] >> SHIFT], 1);
        float x[NIN];
#pragma unroll
        for (int k = 0; k < NIN; ++k) x[k] = p[k];
        int m = 0;
#pragma unroll
        for (int k = 0; k < NIN; ++k) {
            S[k] += x[k];
#pragma unroll
            for (int l = k; l < NIN; ++l) { M[m] = fmaf(x[k], x[l], M[m]); ++m; }
        }
    }
#pragma unroll
    for (int off = 32; off > 0; off >>= 1) {
#pragma unroll
        for (int k = 0; k < NIN; ++k) S[k] += __shfl_xor(S[k], off, 64);
#pragma unroll
        for (int m = 0; m < NMOM; ++m) M[m] += __shfl_xor(M[m], off, 64);
    }
    if (threadIdx.x < 64) red[threadIdx.x] = 0.f;
    __syncthreads();
    if ((threadIdx.x & 63) == 0) {
#pragma unroll
        for (int k = 0; k < NIN; ++k) atomicAdd(&red[WS_S + k], S[k]);
#pragma unroll
        for (int m = 0; m < NMOM; ++m) atomicAdd(&red[WS_M + m], M[m]);
    }
    __syncthreads();
    if (threadIdx.x < 64) atomicAdd(&ws[threadIdx.x], red[threadIdx.x]);
    for (int t = threadIdx.x; t < nb; t += 256)
        if (lhist[t] > 0) atomicAdd(&histc[t], lhist[t]);
}

// ---------------- coarse scan: offsets[0..nb] + cursor copy ----------------
__global__ void scan_coarse_kernel(const int* __restrict__ histc,
                                   int* __restrict__ offsets,
                                   int* __restrict__ cursor, int nb)
{
    __shared__ int part[256];
    const int tid = threadIdx.x;
    int v[4];
    int sum = 0;
    const int base = tid * 4;
#pragma unroll
    for (int j = 0; j < 4; ++j) {
        const int i = base + j;
        v[j] = (i < nb) ? histc[i] : 0;
        sum += v[j];
    }
    part[tid] = sum;
    __syncthreads();
    for (int d = 1; d < 256; d <<= 1) {
        int t = (tid >= d) ? part[tid - d] : 0;
        __syncthreads();
        part[tid] += t;
        __syncthreads();
    }
    int pre = part[tid] - sum;   // exclusive prefix of this thread's chunk
#pragma unroll
    for (int j = 0; j < 4; ++j) {
        const int i = base + j;
        if (i < nb) { offsets[i] = pre; cursor[i] = pre; }
        pre += v[j];
    }
    if (tid == 255) offsets[nb] = part[255];
}

// ---------------- coarse binning: LDS-counted runs, run-reserved, run-written ----------------
__global__ __launch_bounds__(256) void binning_kernel(
    const int* __restrict__ idx, int* __restrict__ cursor,
    int* __restrict__ sidx, int N, int nb)
{
    __shared__ int lcnt[1024];
    __shared__ int runbase[1024];
    const int tid = threadIdx.x;
    const int t0 = blockIdx.x * BTILE;
    for (int t = tid; t < nb; t += 256) lcnt[t] = 0;
    __syncthreads();
#pragma unroll 4
    for (int r = 0; r < BTILE / 256; ++r) {
        const int i = t0 + r * 256 + tid;
        if (i < N) atomicAdd(&lcnt[idx[i] >> SHIFT], 1);
    }
    __syncthreads();
    for (int t = tid; t < nb; t += 256) {
        const int c = lcnt[t];
        if (c > 0) runbase[t] = atomicAdd(&cursor[t], c);
        lcnt[t] = 0;
    }
    __syncthreads();
#pragma unroll 4
    for (int r = 0; r < BTILE / 256; ++r) {
        const int i = t0 + r * 256 + tid;
        if (i < N) {
            const int b = idx[i] >> SHIFT;
            const int p = runbase[b] + atomicAdd(&lcnt[b], 1);
            sidx[p] = i;
        }
    }
}

// ---------------- fine sort (per coarse bucket, in-place, single-XCD window) ----------------
__global__ __launch_bounds__(256) void finesort_kernel(
    const int* __restrict__ idx, const int* __restrict__ offsets,
    int* __restrict__ sidx, int* __restrict__ sseg, int nb)
{
    __shared__ int h[128], off[128], cur[128], tmp[128];
    const int b = blockIdx.x;
    const int tid = threadIdx.x;
    const int start = offsets[b], end = offsets[b + 1];
    const int m = end - start;
    if (m <= 0) return;
    if (m > FCAP) {  // safe fallback: unsorted passthrough (scatter stays correct)
        for (int e = start + tid; e < end; e += 256) sseg[e] = idx[sidx[e]];
        return;
    }
    const int segbase = b << SHIFT;
    if (tid < 128) h[tid] = 0;
    __syncthreads();
    int gi_r[16], f_r[16];
#pragma unroll
    for (int r = 0; r < 16; ++r) {
        const int e = start + r * 256 + tid;
        if (e < end) {
            gi_r[r] = sidx[e];
            f_r[r] = idx[gi_r[r]] - segbase;
            atomicAdd(&h[f_r[r]], 1);
        }
    }
    __syncthreads();
    if (tid < 128) tmp[tid] = h[tid];
    __syncthreads();
    for (int d = 1; d < 128; d <<= 1) {
        int t = (tid < 128 && tid >= d) ? tmp[tid - d] : 0;
        __syncthreads();
        if (tid < 128) tmp[tid] += t;
        __syncthreads();
    }
    if (tid < 128) { off[tid] = tmp[tid] - h[tid]; cur[tid] = 0; }
    __syncthreads();
#pragma unroll
    for (int r = 0; r < 16; ++r) {
        const int e = start + r * 256 + tid;
        if (e < end) {
            const int f = f_r[r];
            const int pos = start + off[f] + atomicAdd(&cur[f], 1);
            sidx[pos] = gi_r[r];
            sseg[pos] = segbase + f;
        }
    }
}

// ---------------- finalize kernels ----------------
__global__ void finalize1_kernel(
    const float* __restrict__ w1, const float* __restrict__ b1,
    const float* __restrict__ g1, const float* __restrict__ be1,
    float* __restrict__ ws, float invN)
{
    __shared__ float sc1s[F1];
    const int j = threadIdx.x;
    if (j < F1) {
        float W[NIN];
        float P = 0.f;
#pragma unroll
        for (int k = 0; k < NIN; ++k) {
            W[k] = w1[k * F1 + j];
            P = fmaf(ws[WS_S + k], W[k], P);
        }
        float Q = 0.f;
        int m = 0;
#pragma unroll
        for (int k = 0; k < NIN; ++k) {
            Q = fmaf(ws[WS_M + m], W[k] * W[k], Q); ++m;
#pragma unroll
            for (int l = k + 1; l < NIN; ++l) {
                Q = fmaf(2.f * ws[WS_M + m], W[k] * W[l], Q); ++m;
            }
        }
        const float b = b1[j];
        const float mean = fmaf(P, invN, b);
        const float Eh2 = fmaf(fmaf(2.f * b, P, Q), invN, b * b);
        const float var = Eh2 - mean * mean;
        const float sc = g1[j] * rsqrtf(var + EPS);
        ws[WS_SC1 + j] = sc;
        ws[WS_SH1 + j] = be1[j] - mean * sc;
        sc1s[j] = sc;
    }
    __syncthreads();
    for (int m = threadIdx.x; m < NIN * F1; m += blockDim.x)
        ws[WS_W1P + m] = w1[m] * sc1s[m & (F1 - 1)];
}

__global__ void finalize2_kernel(
    const float* __restrict__ g2, const float* __restrict__ be2,
    const float* __restrict__ b2, float* __restrict__ ws, float invN, float padf)
{
    const int j = threadIdx.x;
    if (j < F2) {
        const float b = b2[j];
        const float S  = ws[WS_S2 + j]  - padf * b;
        const float SS = ws[WS_SS2 + j] - padf * b * b;
        const float mean = S * invN;
        const float var  = SS * invN - mean * mean;
        const float sc   = g2[j] * rsqrtf(var + EPS);
        ws[WS_SC2 + j] = sc;
        ws[WS_SH2 + j] = be2[j] - mean * sc;
    }
}

// f1 (fp32, uniform scalar weights) -> packed bf16 row (32 bf16 = 4 uint4)
__device__ __forceinline__ void f1_row_bf16(
    const float* __restrict__ p, const float* __restrict__ wl,
    const float* __restrict__ sh1, unsigned int* __restrict__ pk /*[16]*/)
{
    float x[NIN];
#pragma unroll
    for (int k = 0; k < NIN; ++k) x[k] = p[k];
#pragma unroll
    for (int fc = 0; fc < 4; ++fc) {
        float h[8];
#pragma unroll
        for (int jj = 0; jj < 8; ++jj) h[jj] = sh1[fc * 8 + jj];
#pragma unroll
        for (int k = 0; k < NIN; ++k) {
            const float xv = x[k];
#pragma unroll
            for (int jj = 0; jj < 8; ++jj)
                h[jj] = fmaf(xv, wl[k * F1 + fc * 8 + jj], h[jj]);
        }
#pragma unroll
        for (int jj = 0; jj < 4; ++jj)
            pk[fc * 4 + jj] = pack2(fmaxf(h[2 * jj], 0.f), fmaxf(h[2 * jj + 1], 0.f));
    }
}

// ---------------- Pass B: h2 stats via MFMA ----------------
__global__ __launch_bounds__(256, 3) void stats2_kernel(
    const float* __restrict__ pts, const float* __restrict__ w2,
    const float* __restrict__ b2, float* __restrict__ ws, int N)
{
    __shared__ __align__(16) unsigned char f1raw[4][CHUNK * ROWB];
    __shared__ float red[2 * F2];

    const int lane = threadIdx.x & 63, wv = threadIdx.x >> 6;
    const int quad = lane >> 4, m16 = lane & 15;

    bf16x8 bfr[4];
#pragma unroll
    for (int nt = 0; nt < 4; ++nt)
#pragma unroll
        for (int j = 0; j < 8; ++j)
            bfr[nt][j] = (short)f2bf(w2[(quad * 8 + j) * F2 + nt * 16 + m16]);
    float b2f[4];
#pragma unroll
    for (int nt = 0; nt < 4; ++nt) b2f[nt] = b2[nt * 16 + m16];

    const float* wl  = ws + WS_W1P;
    const float* sh1 = ws + WS_SH1;
    const f32x4 zero = {0.f, 0.f, 0.f, 0.f};

    float s[4] = {0.f, 0.f, 0.f, 0.f}, ss[4] = {0.f, 0.f, 0.f, 0.f};

    unsigned char* myf1 = f1raw[wv];
    const int nchunks = (N + CHUNK - 1) / CHUNK;
    for (int c = blockIdx.x * 4 + wv; c < nchunks; c += gridDim.x * 4) {
        const int i = c * CHUNK + lane;
        unsigned int pk[16];
        if (i < N) {
            f1_row_bf16(pts + (size_t)i * NIN, wl, sh1, pk);
        } else {
#pragma unroll
            for (int q = 0; q < 16; ++q) pk[q] = 0u;
        }
        uint4* wrow = (uint4*)(myf1 + lane * ROWB);
#pragma unroll
        for (int cidx = 0; cidx < 4; ++cidx)
            wrow[cidx] = make_uint4(pk[4*cidx+0], pk[4*cidx+1], pk[4*cidx+2], pk[4*cidx+3]);

        bf16x8 afr[4];
#pragma unroll
        for (int mt = 0; mt < 4; ++mt)
            afr[mt] = *(const bf16x8*)(myf1 + (mt * 16 + m16) * ROWB + quad * 16);

#pragma unroll
        for (int mt = 0; mt < 4; ++mt) {
#pragma unroll
            for (int nt = 0; nt < 4; ++nt) {
                f32x4 d = __builtin_amdgcn_mfma_f32_16x16x32_bf16(afr[mt], bfr[nt], zero, 0, 0, 0);
#pragma unroll
                for (int r = 0; r < 4; ++r) {
                    const float v = d[r] + b2f[nt];
                    s[nt] += v;
                    ss[nt] = fmaf(v, v, ss[nt]);
                }
            }
        }
    }

#pragma unroll
    for (int off = 16; off < 64; off <<= 1)
#pragma unroll
        for (int nt = 0; nt < 4; ++nt) {
            s[nt]  += __shfl_xor(s[nt], off, 64);
            ss[nt] += __shfl_xor(ss[nt], off, 64);
        }
    if (threadIdx.x < 2 * F2) red[threadIdx.x] = 0.f;
    __syncthreads();
    if (quad == 0) {
#pragma unroll
        for (int nt = 0; nt < 4; ++nt) {
            atomicAdd(&red[nt * 16 + m16], s[nt]);
            atomicAdd(&red[F2 + nt * 16 + m16], ss[nt]);
        }
    }
    __syncthreads();
    if (threadIdx.x < F2) {
        atomicAdd(&ws[WS_S2 + threadIdx.x],  red[threadIdx.x]);
        atomicAdd(&ws[WS_SS2 + threadIdx.x], red[F2 + threadIdx.x]);
    }
}

// ---------------- Pass C: sorted points, MFMA + run-aggregated atomicMax ----------------
__global__ __launch_bounds__(256, 3) void scatter_kernel(
    const float* __restrict__ pts, const int* __restrict__ sidx,
    const int* __restrict__ sseg, const float* __restrict__ w2,
    const float* __restrict__ b2, const float* __restrict__ ws,
    unsigned int* __restrict__ out, int N)
{
    __shared__ __align__(16) unsigned char f1raw[4][CHUNK * ROWB];
    __shared__ float f2win[4][16 * F2STRIDE];
    __shared__ int segt[4][CHUNK];

    const int lane = threadIdx.x & 63, wv = threadIdx.x >> 6;
    const int quad = lane >> 4, m16 = lane & 15;

    bf16x8 bfr[4];
#pragma unroll
    for (int nt = 0; nt < 4; ++nt)
#pragma unroll
        for (int j = 0; j < 8; ++j)
            bfr[nt][j] = (short)f2bf(w2[(quad * 8 + j) * F2 + nt * 16 + m16]);

    float sc2f[4], shb[4];
#pragma unroll
    for (int nt = 0; nt < 4; ++nt) {
        const int f = nt * 16 + m16;
        sc2f[nt] = ws[WS_SC2 + f];
        shb[nt]  = fmaf(b2[f], sc2f[nt], ws[WS_SH2 + f]);
    }

    const float* wl  = ws + WS_W1P;
    const float* sh1 = ws + WS_SH1;
    const f32x4 zero = {0.f, 0.f, 0.f, 0.f};

    unsigned char* myf1 = f1raw[wv];
    float* myf2 = f2win[wv];
    int* myseg = segt[wv];
    const int nchunks = (N + CHUNK - 1) / CHUNK;
    for (int c = blockIdx.x * 4 + wv; c < nchunks; c += gridDim.x * 4) {
        const int sp = c * CHUNK + lane;
        unsigned int pk[16];
        int sg = -1;
        if (sp < N) {
            const int gi = sidx[sp];
            f1_row_bf16(pts + (size_t)gi * NIN, wl, sh1, pk);
            sg = sseg[sp];
        } else {
#pragma unroll
            for (int q = 0; q < 16; ++q) pk[q] = 0u;
        }
        uint4* wrow = (uint4*)(myf1 + lane * ROWB);
#pragma unroll
        for (int cidx = 0; cidx < 4; ++cidx)
            wrow[cidx] = make_uint4(pk[4*cidx+0], pk[4*cidx+1], pk[4*cidx+2], pk[4*cidx+3]);
        myseg[lane] = sg;

        bf16x8 afr[4];
#pragma unroll
        for (int mt = 0; mt < 4; ++mt)
            afr[mt] = *(const bf16x8*)(myf1 + (mt * 16 + m16) * ROWB + quad * 16);

        int cur = -1;
        float acc = -3.4e38f;
#pragma unroll
        for (int mt = 0; mt < 4; ++mt) {
            f32x4 d[4];
#pragma unroll
            for (int nt = 0; nt < 4; ++nt)
                d[nt] = __builtin_amdgcn_mfma_f32_16x16x32_bf16(afr[mt], bfr[nt], zero, 0, 0, 0);
#pragma unroll
            for (int r = 0; r < 4; ++r)
#pragma unroll
                for (int nt = 0; nt < 4; ++nt)
                    myf2[(quad * 4 + r) * F2STRIDE + nt * 16 + m16] =
                        fmaf(d[nt][r], sc2f[nt], shb[nt]);
            for (int p = 0; p < 16; ++p) {
                const int sg2 = myseg[mt * 16 + p];
                const float v = myf2[p * F2STRIDE + lane];
                if (sg2 != cur) {
                    if (cur >= 0 && acc > 0.f)
                        atomicMax(out + (size_t)cur * F2 + lane, __float_as_uint(acc));
                    cur = sg2;
                    acc = v;
                } else {
                    acc = fmaxf(acc, v);
                }
            }
        }
        if (cur >= 0 && acc > 0.f)
            atomicMax(out + (size_t)cur * F2 + lane, __float_as_uint(acc));
    }
}

extern "C" void kernel_launch(void* const* d_in, const int* in_sizes, int n_in,
                              void* d_out, int out_size, void* d_ws, size_t ws_size,
                              hipStream_t stream)
{
    const float* pts = (const float*)d_in[0];
    const int*   idx = (const int*)d_in[1];
    const float* w1  = (const float*)d_in[3];
    const float* b1  = (const float*)d_in[4];
    const float* g1  = (const float*)d_in[5];
    const float* be1 = (const float*)d_in[6];
    const float* w2  = (const float*)d_in[7];
    const float* b2  = (const float*)d_in[8];
    const float* g2  = (const float*)d_in[9];
    const float* be2 = (const float*)d_in[10];

    float* ws = (float*)d_ws;
    const int N = in_sizes[0] / NIN;
    const int nseg = out_size / F2;
    const int nb = (nseg + (1 << SHIFT) - 1) >> SHIFT;   // coarse buckets (<=1024)
    const float invN = 1.0f / (float)N;
    const float padf = (float)((CHUNK - (N % CHUNK)) % CHUNK);

    // int scratch after the 1024-float param region
    int* histc   = (int*)d_ws + 1024;   // 1024
    int* offsets = histc + 1024;        // nb+1 (<=1025)
    int* cursor  = offsets + 1025;      // 1024
    int* sidx    = cursor + 1024;       // N
    int* sseg    = sidx + N;            // N

    hipMemsetAsync(ws, 0, 192 * sizeof(float), stream);
    hipMemsetAsync(histc, 0, 1024 * sizeof(int), stream);
    hipMemsetAsync(d_out, 0, (size_t)out_size * sizeof(float), stream);

    moments_kernel<<<1024, 256, 0, stream>>>(pts, idx, ws, histc, N, nb);
    finalize1_kernel<<<1, 320, 0, stream>>>(w1, b1, g1, be1, ws, invN);

    scan_coarse_kernel<<<1, 256, 0, stream>>>(histc, offsets, cursor, nb);
    binning_kernel<<<(N + BTILE - 1) / BTILE, 256, 0, stream>>>(idx, cursor, sidx, N, nb);
    finesort_kernel<<<nb, 256, 0, stream>>>(idx, offsets, sidx, sseg, nb);

    stats2_kernel<<<1024, 256, 0, stream>>>(pts, w2, b2, ws, N);
    finalize2_kernel<<<1, 64, 0, stream>>>(g2, be2, b2, ws, invN, padf);
    scatter_kernel<<<1024, 256, 0, stream>>>(pts, sidx, sseg, w2, b2, ws,
                                             (unsigned int*)d_out, N);
}

// Round 7
// 329.551 us; speedup vs baseline: 3.6170x; 1.0738x over previous
//
#include <hip/hip_runtime.h>

#define EPS 1e-5f
#define NIN 9
#define F1 32
#define F2 64
#define NMOM 45
#define ROWB 80       // bytes per bf16 f1 row in LDS staging
#define SHIFT 7       // coarse bucket = seg >> 7 (128 segs/bucket)
#define NSEGB 128     // segs per bucket
#define NBMAX 1024
#define BT_MAIN 2048  // points per binf1 workgroup
#define BT_FB 8192    // points per fallback binning workgroup
#define WSTRIDE 68    // dwords per window row (padded)

// params region float offsets
#define WS_S    0
#define WS_M    16
#define WS_S2   64
#define WS_SS2  128
#define WS_SC1  192
#define WS_SH1  224
#define WS_W1P  256
#define WS_SC2  544
#define WS_SH2  608

typedef __attribute__((ext_vector_type(8))) short bf16x8;
typedef __attribute__((ext_vector_type(4))) float f32x4;

__device__ __forceinline__ unsigned int f2bf(float f) {
    unsigned int u = __float_as_uint(f);
    return (u + 0x7fffu + ((u >> 16) & 1u)) >> 16;   // RNE
}
__device__ __forceinline__ unsigned int pack2(float lo, float hi) {
    return f2bf(lo) | (f2bf(hi) << 16);
}

// ---------------- Pass A: x moments + coarse segment histogram ----------------
__global__ __launch_bounds__(256, 4) void moments_kernel(
    const float* __restrict__ pts, const int* __restrict__ idx,
    float* __restrict__ ws, int* __restrict__ histc, int N, int nb)
{
    __shared__ int lhist[NBMAX];
    __shared__ float red[64];
    for (int t = threadIdx.x; t < nb; t += 256) lhist[t] = 0;

    float S[NIN], M[NMOM];
#pragma unroll
    for (int k = 0; k < NIN; ++k) S[k] = 0.f;
#pragma unroll
    for (int m = 0; m < NMOM; ++m) M[m] = 0.f;
    __syncthreads();

    const int stride = gridDim.x * blockDim.x;
    for (int i = blockIdx.x * blockDim.x + threadIdx.x; i < N; i += stride) {
        const float* p = pts + (size_t)i * NIN;
        atomicAdd(&lhist[idx[i] >> SHIFT], 1);
        float x[NIN];
#pragma unroll
        for (int k = 0; k < NIN; ++k) x[k] = p[k];
        int m = 0;
#pragma unroll
        for (int k = 0; k < NIN; ++k) {
            S[k] += x[k];
#pragma unroll
            for (int l = k; l < NIN; ++l) { M[m] = fmaf(x[k], x[l], M[m]); ++m; }
        }
    }
#pragma unroll
    for (int off = 32; off > 0; off >>= 1) {
#pragma unroll
        for (int k = 0; k < NIN; ++k) S[k] += __shfl_xor(S[k], off, 64);
#pragma unroll
        for (int m = 0; m < NMOM; ++m) M[m] += __shfl_xor(M[m], off, 64);
    }
    if (threadIdx.x < 64) red[threadIdx.x] = 0.f;
    __syncthreads();
    if ((threadIdx.x & 63) == 0) {
#pragma unroll
        for (int k = 0; k < NIN; ++k) atomicAdd(&red[WS_S + k], S[k]);
#pragma unroll
        for (int m = 0; m < NMOM; ++m) atomicAdd(&red[WS_M + m], M[m]);
    }
    __syncthreads();
    if (threadIdx.x < 64) atomicAdd(&ws[threadIdx.x], red[threadIdx.x]);
    for (int t = threadIdx.x; t < nb; t += 256)
        if (lhist[t] > 0) atomicAdd(&histc[t], lhist[t]);
}

// ---------------- coarse scan: offsets[0..nb] + cursor copy ----------------
__global__ void scan_coarse_kernel(const int* __restrict__ histc,
                                   int* __restrict__ offsets,
                                   int* __restrict__ cursor, int nb)
{
    __shared__ int part[256];
    const int tid = threadIdx.x;
    int v[4];
    int sum = 0;
    const int base = tid * 4;
#pragma unroll
    for (int j = 0; j < 4; ++j) {
        const int i = base + j;
        v[j] = (i < nb) ? histc[i] : 0;
        sum += v[j];
    }
    part[tid] = sum;
    __syncthreads();
    for (int d = 1; d < 256; d <<= 1) {
        int t = (tid >= d) ? part[tid - d] : 0;
        __syncthreads();
        part[tid] += t;
        __syncthreads();
    }
    int pre = part[tid] - sum;
#pragma unroll
    for (int j = 0; j < 4; ++j) {
        const int i = base + j;
        if (i < nb) { offsets[i] = pre; cursor[i] = pre; }
        pre += v[j];
    }
    if (tid == 255) offsets[nb] = part[255];
}

// ---------------- finalize kernels ----------------
__global__ void finalize1_kernel(
    const float* __restrict__ w1, const float* __restrict__ b1,
    const float* __restrict__ g1, const float* __restrict__ be1,
    float* __restrict__ ws, float invN)
{
    __shared__ float sc1s[F1];
    const int j = threadIdx.x;
    if (j < F1) {
        float W[NIN];
        float P = 0.f;
#pragma unroll
        for (int k = 0; k < NIN; ++k) {
            W[k] = w1[k * F1 + j];
            P = fmaf(ws[WS_S + k], W[k], P);
        }
        float Q = 0.f;
        int m = 0;
#pragma unroll
        for (int k = 0; k < NIN; ++k) {
            Q = fmaf(ws[WS_M + m], W[k] * W[k], Q); ++m;
#pragma unroll
            for (int l = k + 1; l < NIN; ++l) {
                Q = fmaf(2.f * ws[WS_M + m], W[k] * W[l], Q); ++m;
            }
        }
        const float b = b1[j];
        const float mean = fmaf(P, invN, b);
        const float Eh2 = fmaf(fmaf(2.f * b, P, Q), invN, b * b);
        const float var = Eh2 - mean * mean;
        const float sc = g1[j] * rsqrtf(var + EPS);
        ws[WS_SC1 + j] = sc;
        ws[WS_SH1 + j] = be1[j] - mean * sc;
        sc1s[j] = sc;
    }
    __syncthreads();
    for (int m = threadIdx.x; m < NIN * F1; m += blockDim.x)
        ws[WS_W1P + m] = w1[m] * sc1s[m & (F1 - 1)];
}

__global__ void finalize2_kernel(
    const float* __restrict__ g2, const float* __restrict__ be2,
    const float* __restrict__ b2, float* __restrict__ ws, float invN, float padf)
{
    const int j = threadIdx.x;
    if (j < F2) {
        const float b = b2[j];
        const float S  = ws[WS_S2 + j]  - padf * b;
        const float SS = ws[WS_SS2 + j] - padf * b * b;
        const float mean = S * invN;
        const float var  = SS * invN - mean * mean;
        const float sc   = g2[j] * rsqrtf(var + EPS);
        ws[WS_SC2 + j] = sc;
        ws[WS_SH2 + j] = be2[j] - mean * sc;
    }
}

// f1 (fp32, uniform scalar weights) -> packed bf16 row (32 bf16 = 4 uint4)
__device__ __forceinline__ void f1_row_bf16(
    const float* __restrict__ p, const float* __restrict__ wl,
    const float* __restrict__ sh1, unsigned int* __restrict__ pk /*[16]*/)
{
    float x[NIN];
#pragma unroll
    for (int k = 0; k < NIN; ++k) x[k] = p[k];
#pragma unroll
    for (int fc = 0; fc < 4; ++fc) {
        float h[8];
#pragma unroll
        for (int jj = 0; jj < 8; ++jj) h[jj] = sh1[fc * 8 + jj];
#pragma unroll
        for (int k = 0; k < NIN; ++k) {
            const float xv = x[k];
#pragma unroll
            for (int jj = 0; jj < 8; ++jj)
                h[jj] = fmaf(xv, wl[k * F1 + fc * 8 + jj], h[jj]);
        }
#pragma unroll
        for (int jj = 0; jj < 4; ++jj)
            pk[fc * 4 + jj] = pack2(fmaxf(h[2 * jj], 0.f), fmaxf(h[2 * jj + 1], 0.f));
    }
}

// ---------------- MAIN: binning + f1 materialization + fused h2 stats ----------------
__global__ __launch_bounds__(256, 3) void binf1_kernel(
    const float* __restrict__ pts, const int* __restrict__ idx,
    const float* __restrict__ w2, const float* __restrict__ b2,
    float* __restrict__ ws, int* __restrict__ cursor,
    uint4* __restrict__ f1buf, int* __restrict__ fseg, int N, int nb)
{
    __shared__ int lcnt[NBMAX], runbase[NBMAX];
    __shared__ __align__(16) unsigned char stag[4][64 * ROWB];
    __shared__ float red[2 * F2];

    const int tid = threadIdx.x;
    const int t0 = blockIdx.x * BT_MAIN;
    const int lane = tid & 63, wv = tid >> 6;
    const int quad = lane >> 4, m16 = lane & 15;

    for (int t = tid; t < nb; t += 256) lcnt[t] = 0;
    __syncthreads();
#pragma unroll
    for (int r = 0; r < BT_MAIN / 256; ++r) {
        const int i = t0 + r * 256 + tid;
        if (i < N) atomicAdd(&lcnt[idx[i] >> SHIFT], 1);
    }
    __syncthreads();
    for (int t = tid; t < nb; t += 256) {
        const int c = lcnt[t];
        if (c > 0) runbase[t] = atomicAdd(&cursor[t], c);
        lcnt[t] = 0;
    }
    __syncthreads();

    bf16x8 bfr[4];
#pragma unroll
    for (int nt = 0; nt < 4; ++nt)
#pragma unroll
        for (int j = 0; j < 8; ++j)
            bfr[nt][j] = (short)f2bf(w2[(quad * 8 + j) * F2 + nt * 16 + m16]);
    float b2f[4];
#pragma unroll
    for (int nt = 0; nt < 4; ++nt) b2f[nt] = b2[nt * 16 + m16];

    const float* wl  = ws + WS_W1P;
    const float* sh1 = ws + WS_SH1;
    const f32x4 zero = {0.f, 0.f, 0.f, 0.f};
    float s[4] = {0.f, 0.f, 0.f, 0.f}, ss[4] = {0.f, 0.f, 0.f, 0.f};
    unsigned char* myst = stag[wv];

#pragma unroll 1
    for (int r = 0; r < BT_MAIN / 256; ++r) {
        const int cstart = t0 + r * 256 + wv * 64;
        if (cstart >= N) continue;
        const int i = cstart + lane;
        unsigned int pk[16];
        if (i < N) {
            f1_row_bf16(pts + (size_t)i * NIN, wl, sh1, pk);
        } else {
#pragma unroll
            for (int q = 0; q < 16; ++q) pk[q] = 0u;
        }
        uint4* wrow = (uint4*)(myst + lane * ROWB);
#pragma unroll
        for (int cidx = 0; cidx < 4; ++cidx)
            wrow[cidx] = make_uint4(pk[4*cidx+0], pk[4*cidx+1], pk[4*cidx+2], pk[4*cidx+3]);

        if (i < N) {
            const int sg = idx[i];
            const int bb = sg >> SHIFT;
            const int p = runbase[bb] + atomicAdd(&lcnt[bb], 1);
            uint4* dst = f1buf + (size_t)p * 4;
            dst[0] = make_uint4(pk[0],  pk[1],  pk[2],  pk[3]);
            dst[1] = make_uint4(pk[4],  pk[5],  pk[6],  pk[7]);
            dst[2] = make_uint4(pk[8],  pk[9],  pk[10], pk[11]);
            dst[3] = make_uint4(pk[12], pk[13], pk[14], pk[15]);
            fseg[p] = sg;
        }

        bf16x8 afr[4];
#pragma unroll
        for (int mt = 0; mt < 4; ++mt)
            afr[mt] = *(const bf16x8*)(myst + (mt * 16 + m16) * ROWB + quad * 16);
#pragma unroll
        for (int mt = 0; mt < 4; ++mt) {
#pragma unroll
            for (int nt = 0; nt < 4; ++nt) {
                f32x4 d = __builtin_amdgcn_mfma_f32_16x16x32_bf16(afr[mt], bfr[nt], zero, 0, 0, 0);
#pragma unroll
                for (int rr = 0; rr < 4; ++rr) {
                    const float v = d[rr] + b2f[nt];
                    s[nt] += v;
                    ss[nt] = fmaf(v, v, ss[nt]);
                }
            }
        }
    }

#pragma unroll
    for (int off = 16; off < 64; off <<= 1)
#pragma unroll
        for (int nt = 0; nt < 4; ++nt) {
            s[nt]  += __shfl_xor(s[nt], off, 64);
            ss[nt] += __shfl_xor(ss[nt], off, 64);
        }
    if (tid < 2 * F2) red[tid] = 0.f;
    __syncthreads();
    if (quad == 0) {
#pragma unroll
        for (int nt = 0; nt < 4; ++nt) {
            atomicAdd(&red[nt * 16 + m16], s[nt]);
            atomicAdd(&red[F2 + nt * 16 + m16], ss[nt]);
        }
    }
    __syncthreads();
    if (tid < F2) {
        atomicAdd(&ws[WS_S2 + tid],  red[tid]);
        atomicAdd(&ws[WS_SS2 + tid], red[F2 + tid]);
    }
}

// ---------------- MAIN: per-bucket LDS-window scatter (no global atomics) ----------------
__global__ __launch_bounds__(256, 3) void bucket_scatter_kernel(
    const uint4* __restrict__ f1buf, const int* __restrict__ fseg,
    const float* __restrict__ w2, const float* __restrict__ b2,
    const float* __restrict__ ws, const int* __restrict__ offsets,
    unsigned int* __restrict__ out, int nseg)
{
    __shared__ unsigned int win[NSEGB * WSTRIDE];
    __shared__ int segl[4][64];

    const int b = blockIdx.x;
    const int start = offsets[b], end = offsets[b + 1];
    const int tid = threadIdx.x;
    const int lane = tid & 63, wv = tid >> 6;
    const int quad = lane >> 4, m16 = lane & 15;

    for (int t = tid; t < NSEGB * WSTRIDE; t += 256) win[t] = 0u;

    bf16x8 bfr[4];
#pragma unroll
    for (int nt = 0; nt < 4; ++nt)
#pragma unroll
        for (int j = 0; j < 8; ++j)
            bfr[nt][j] = (short)f2bf(w2[(quad * 8 + j) * F2 + nt * 16 + m16]);
    float sc2f[4], shb[4];
#pragma unroll
    for (int nt = 0; nt < 4; ++nt) {
        const int f = nt * 16 + m16;
        sc2f[nt] = ws[WS_SC2 + f];
        shb[nt]  = fmaf(b2[f], sc2f[nt], ws[WS_SH2 + f]);
    }
    const f32x4 zero = {0.f, 0.f, 0.f, 0.f};
    __syncthreads();

    const int segbase = b << SHIFT;
    const int nch = (end - start + 63) >> 6;
    const bf16x8* fb = (const bf16x8*)f1buf;
    for (int c = wv; c < nch; c += 4) {
        const int cbase = start + c * 64;
        segl[wv][lane] = (cbase + lane < end) ? (fseg[cbase + lane] - segbase) : -1;
        bf16x8 afr[4];
#pragma unroll
        for (int mt = 0; mt < 4; ++mt) {
            const int ri = cbase + mt * 16 + m16;
            if (ri < end) {
                afr[mt] = fb[(size_t)ri * 4 + quad];
            } else {
#pragma unroll
                for (int j = 0; j < 8; ++j) afr[mt][j] = 0;
            }
        }
#pragma unroll
        for (int mt = 0; mt < 4; ++mt) {
            f32x4 d[4];
#pragma unroll
            for (int nt = 0; nt < 4; ++nt)
                d[nt] = __builtin_amdgcn_mfma_f32_16x16x32_bf16(afr[mt], bfr[nt], zero, 0, 0, 0);
#pragma unroll
            for (int rr = 0; rr < 4; ++rr) {
                const int sl = segl[wv][mt * 16 + quad * 4 + rr];
                if (sl >= 0) {
#pragma unroll
                    for (int nt = 0; nt < 4; ++nt) {
                        const float v = fmaf(d[nt][rr], sc2f[nt], shb[nt]);
                        if (v > 0.f)
                            atomicMax(&win[sl * WSTRIDE + nt * 16 + m16], __float_as_uint(v));
                    }
                }
            }
        }
    }
    __syncthreads();
    const int rows = min(NSEGB, nseg - segbase);
    for (int t = tid; t < rows * 64; t += 256)
        out[(size_t)(segbase + (t >> 6)) * 64 + (t & 63)] = win[(t >> 6) * WSTRIDE + (t & 63)];
}

// ---------------- FALLBACK: binning writing sidx+fseg ----------------
__global__ __launch_bounds__(256) void binning_fb_kernel(
    const int* __restrict__ idx, int* __restrict__ cursor,
    int* __restrict__ sidx, int* __restrict__ fseg, int N, int nb)
{
    __shared__ int lcnt[NBMAX];
    __shared__ int runbase[NBMAX];
    const int tid = threadIdx.x;
    const int t0 = blockIdx.x * BT_FB;
    for (int t = tid; t < nb; t += 256) lcnt[t] = 0;
    __syncthreads();
#pragma unroll 4
    for (int r = 0; r < BT_FB / 256; ++r) {
        const int i = t0 + r * 256 + tid;
        if (i < N) atomicAdd(&lcnt[idx[i] >> SHIFT], 1);
    }
    __syncthreads();
    for (int t = tid; t < nb; t += 256) {
        const int c = lcnt[t];
        if (c > 0) runbase[t] = atomicAdd(&cursor[t], c);
        lcnt[t] = 0;
    }
    __syncthreads();
#pragma unroll 4
    for (int r = 0; r < BT_FB / 256; ++r) {
        const int i = t0 + r * 256 + tid;
        if (i < N) {
            const int sg = idx[i];
            const int bb = sg >> SHIFT;
            const int p = runbase[bb] + atomicAdd(&lcnt[bb], 1);
            sidx[p] = i;
            fseg[p] = sg;
        }
    }
}

// ---------------- FALLBACK: standalone h2 stats ----------------
__global__ __launch_bounds__(256, 3) void stats2_kernel(
    const float* __restrict__ pts, const float* __restrict__ w2,
    const float* __restrict__ b2, float* __restrict__ ws, int N)
{
    __shared__ __align__(16) unsigned char stag[4][64 * ROWB];
    __shared__ float red[2 * F2];

    const int lane = threadIdx.x & 63, wv = threadIdx.x >> 6;
    const int quad = lane >> 4, m16 = lane & 15;

    bf16x8 bfr[4];
#pragma unroll
    for (int nt = 0; nt < 4; ++nt)
#pragma unroll
        for (int j = 0; j < 8; ++j)
            bfr[nt][j] = (short)f2bf(w2[(quad * 8 + j) * F2 + nt * 16 + m16]);
    float b2f[4];
#pragma unroll
    for (int nt = 0; nt < 4; ++nt) b2f[nt] = b2[nt * 16 + m16];

    const float* wl  = ws + WS_W1P;
    const float* sh1 = ws + WS_SH1;
    const f32x4 zero = {0.f, 0.f, 0.f, 0.f};
    float s[4] = {0.f, 0.f, 0.f, 0.f}, ss[4] = {0.f, 0.f, 0.f, 0.f};

    unsigned char* myst = stag[wv];
    const int nchunks = (N + 63) / 64;
    for (int c = blockIdx.x * 4 + wv; c < nchunks; c += gridDim.x * 4) {
        const int i = c * 64 + lane;
        unsigned int pk[16];
        if (i < N) {
            f1_row_bf16(pts + (size_t)i * NIN, wl, sh1, pk);
        } else {
#pragma unroll
            for (int q = 0; q < 16; ++q) pk[q] = 0u;
        }
        uint4* wrow = (uint4*)(myst + lane * ROWB);
#pragma unroll
        for (int cidx = 0; cidx < 4; ++cidx)
            wrow[cidx] = make_uint4(pk[4*cidx+0], pk[4*cidx+1], pk[4*cidx+2], pk[4*cidx+3]);

        bf16x8 afr[4];
#pragma unroll
        for (int mt = 0; mt < 4; ++mt)
            afr[mt] = *(const bf16x8*)(myst + (mt * 16 + m16) * ROWB + quad * 16);
#pragma unroll
        for (int mt = 0; mt < 4; ++mt) {
#pragma unroll
            for (int nt = 0; nt < 4; ++nt) {
                f32x4 d = __builtin_amdgcn_mfma_f32_16x16x32_bf16(afr[mt], bfr[nt], zero, 0, 0, 0);
#pragma unroll
                for (int rr = 0; rr < 4; ++rr) {
                    const float v = d[rr] + b2f[nt];
                    s[nt] += v;
                    ss[nt] = fmaf(v, v, ss[nt]);
                }
            }
        }
    }
#pragma unroll
    for (int off = 16; off < 64; off <<= 1)
#pragma unroll
        for (int nt = 0; nt < 4; ++nt) {
            s[nt]  += __shfl_xor(s[nt], off, 64);
            ss[nt] += __shfl_xor(ss[nt], off, 64);
        }
    if (threadIdx.x < 2 * F2) red[threadIdx.x] = 0.f;
    __syncthreads();
    if (quad == 0) {
#pragma unroll
        for (int nt = 0; nt < 4; ++nt) {
            atomicAdd(&red[nt * 16 + m16], s[nt]);
            atomicAdd(&red[F2 + nt * 16 + m16], ss[nt]);
        }
    }
    __syncthreads();
    if (threadIdx.x < F2) {
        atomicAdd(&ws[WS_S2 + threadIdx.x],  red[threadIdx.x]);
        atomicAdd(&ws[WS_SS2 + threadIdx.x], red[F2 + threadIdx.x]);
    }
}

// ---------------- FALLBACK: per-bucket window scatter with pts gather ----------------
__global__ __launch_bounds__(256, 2) void bucket_scatter_gather_kernel(
    const float* __restrict__ pts, const int* __restrict__ sidx,
    const int* __restrict__ fseg, const float* __restrict__ w2,
    const float* __restrict__ b2, const float* __restrict__ ws,
    const int* __restrict__ offsets, unsigned int* __restrict__ out, int nseg)
{
    __shared__ unsigned int win[NSEGB * WSTRIDE];
    __shared__ __align__(16) unsigned char stag[4][64 * ROWB];
    __shared__ int segl[4][64];

    const int b = blockIdx.x;
    const int start = offsets[b], end = offsets[b + 1];
    const int tid = threadIdx.x;
    const int lane = tid & 63, wv = tid >> 6;
    const int quad = lane >> 4, m16 = lane & 15;

    for (int t = tid; t < NSEGB * WSTRIDE; t += 256) win[t] = 0u;

    bf16x8 bfr[4];
#pragma unroll
    for (int nt = 0; nt < 4; ++nt)
#pragma unroll
        for (int j = 0; j < 8; ++j)
            bfr[nt][j] = (short)f2bf(w2[(quad * 8 + j) * F2 + nt * 16 + m16]);
    float sc2f[4], shb[4];
#pragma unroll
    for (int nt = 0; nt < 4; ++nt) {
        const int f = nt * 16 + m16;
        sc2f[nt] = ws[WS_SC2 + f];
        shb[nt]  = fmaf(b2[f], sc2f[nt], ws[WS_SH2 + f]);
    }
    const float* wl  = ws + WS_W1P;
    const float* sh1 = ws + WS_SH1;
    const f32x4 zero = {0.f, 0.f, 0.f, 0.f};
    __syncthreads();

    const int segbase = b << SHIFT;
    const int nch = (end - start + 63) >> 6;
    unsigned char* myst = stag[wv];
    for (int c = wv; c < nch; c += 4) {
        const int cbase = start + c * 64;
        const int sp = cbase + lane;
        unsigned int pk[16];
        int sl = -1;
        if (sp < end) {
            f1_row_bf16(pts + (size_t)sidx[sp] * NIN, wl, sh1, pk);
            sl = fseg[sp] - segbase;
        } else {
#pragma unroll
            for (int q = 0; q < 16; ++q) pk[q] = 0u;
        }
        segl[wv][lane] = sl;
        uint4* wrow = (uint4*)(myst + lane * ROWB);
#pragma unroll
        for (int cidx = 0; cidx < 4; ++cidx)
            wrow[cidx] = make_uint4(pk[4*cidx+0], pk[4*cidx+1], pk[4*cidx+2], pk[4*cidx+3]);

        bf16x8 afr[4];
#pragma unroll
        for (int mt = 0; mt < 4; ++mt)
            afr[mt] = *(const bf16x8*)(myst + (mt * 16 + m16) * ROWB + quad * 16);
#pragma unroll
        for (int mt = 0; mt < 4; ++mt) {
            f32x4 d[4];
#pragma unroll
            for (int nt = 0; nt < 4; ++nt)
                d[nt] = __builtin_amdgcn_mfma_f32_16x16x32_bf16(afr[mt], bfr[nt], zero, 0, 0, 0);
#pragma unroll
            for (int rr = 0; rr < 4; ++rr) {
                const int sl2 = segl[wv][mt * 16 + quad * 4 + rr];
                if (sl2 >= 0) {
#pragma unroll
                    for (int nt = 0; nt < 4; ++nt) {
                        const float v = fmaf(d[nt][rr], sc2f[nt], shb[nt]);
                        if (v > 0.f)
                            atomicMax(&win[sl2 * WSTRIDE + nt * 16 + m16], __float_as_uint(v));
                    }
                }
            }
        }
    }
    __syncthreads();
    const int rows = min(NSEGB, nseg - segbase);
    for (int t = tid; t < rows * 64; t += 256)
        out[(size_t)(segbase + (t >> 6)) * 64 + (t & 63)] = win[(t >> 6) * WSTRIDE + (t & 63)];
}

extern "C" void kernel_launch(void* const* d_in, const int* in_sizes, int n_in,
                              void* d_out, int out_size, void* d_ws, size_t ws_size,
                              hipStream_t stream)
{
    const float* pts = (const float*)d_in[0];
    const int*   idx = (const int*)d_in[1];
    const float* w1  = (const float*)d_in[3];
    const float* b1  = (const float*)d_in[4];
    const float* g1  = (const float*)d_in[5];
    const float* be1 = (const float*)d_in[6];
    const float* w2  = (const float*)d_in[7];
    const float* b2  = (const float*)d_in[8];
    const float* g2  = (const float*)d_in[9];
    const float* be2 = (const float*)d_in[10];

    const int N = in_sizes[0] / NIN;
    const int nseg = out_size / F2;
    const int nb = (nseg + NSEGB - 1) >> SHIFT;
    const float invN = 1.0f / (float)N;
    const float padf = (float)((64 - (N & 63)) & 63);

    char* base = (char*)d_ws;
    const size_t f1bytes = (size_t)N * 64;
    const size_t need_main = f1bytes + 4096
                           + ((size_t)NBMAX + NBMAX + 1 + NBMAX + N) * sizeof(int) + 256;

    if (ws_size >= need_main) {
        // ---- main path: f1 materialization ----
        uint4* f1buf   = (uint4*)base;
        float* ws      = (float*)(base + f1bytes);
        int*   histc   = (int*)(base + f1bytes + 4096);
        int*   offsets = histc + NBMAX;
        int*   cursor  = offsets + NBMAX + 1;
        int*   fseg    = cursor + NBMAX;

        hipMemsetAsync(ws, 0, 192 * sizeof(float), stream);
        hipMemsetAsync(histc, 0, NBMAX * sizeof(int), stream);

        moments_kernel<<<1024, 256, 0, stream>>>(pts, idx, ws, histc, N, nb);
        finalize1_kernel<<<1, 320, 0, stream>>>(w1, b1, g1, be1, ws, invN);
        scan_coarse_kernel<<<1, 256, 0, stream>>>(histc, offsets, cursor, nb);
        binf1_kernel<<<(N + BT_MAIN - 1) / BT_MAIN, 256, 0, stream>>>(
            pts, idx, w2, b2, ws, cursor, f1buf, fseg, N, nb);
        finalize2_kernel<<<1, 64, 0, stream>>>(g2, be2, b2, ws, invN, padf);
        bucket_scatter_kernel<<<nb, 256, 0, stream>>>(
            f1buf, fseg, w2, b2, ws, offsets, (unsigned int*)d_out, nseg);
    } else {
        // ---- fallback path: index sort + gather ----
        float* ws      = (float*)base;
        int*   histc   = (int*)(base + 4096);
        int*   offsets = histc + NBMAX;
        int*   cursor  = offsets + NBMAX + 1;
        int*   sidx    = cursor + NBMAX;
        int*   fseg    = sidx + N;

        hipMemsetAsync(ws, 0, 192 * sizeof(float), stream);
        hipMemsetAsync(histc, 0, NBMAX * sizeof(int), stream);

        moments_kernel<<<1024, 256, 0, stream>>>(pts, idx, ws, histc, N, nb);
        finalize1_kernel<<<1, 320, 0, stream>>>(w1, b1, g1, be1, ws, invN);
        scan_coarse_kernel<<<1, 256, 0, stream>>>(histc, offsets, cursor, nb);
        binning_fb_kernel<<<(N + BT_FB - 1) / BT_FB, 256, 0, stream>>>(
            idx, cursor, sidx, fseg, N, nb);
        stats2_kernel<<<1024, 256, 0, stream>>>(pts, w2, b2, ws, N);
        finalize2_kernel<<<1, 64, 0, stream>>>(g2, be2, b2, ws, invN, padf);
        bucket_scatter_gather_kernel<<<nb, 256, 0, stream>>>(
            pts, sidx, fseg, w2, b2, ws, offsets, (unsigned int*)d_out, nseg);
    }
}

// Round 8
// 307.157 us; speedup vs baseline: 3.8807x; 1.0729x over previous
//
#include <hip/hip_runtime.h>

#define EPS 1e-5f
#define NIN 9
#define F1 32
#define F2 64
#define NMOM 45
#define ROWB 80       // bytes per bf16 f1 row in LDS staging
#define SHIFT 7       // coarse bucket = seg >> 7 (128 segs/bucket)
#define NSEGB 128     // segs per bucket
#define NBMAX 1024
#define BT_BIN 8192   // points per binning workgroup
#define WSTRIDE 68    // dwords per window row (padded)

// params region float offsets
#define WS_S    0
#define WS_M    16
#define WS_S2   64
#define WS_SS2  128
#define WS_SC1  192
#define WS_SH1  224
#define WS_W1P  256
#define WS_SC2  544
#define WS_SH2  608

typedef __attribute__((ext_vector_type(8))) short bf16x8;
typedef __attribute__((ext_vector_type(4))) float f32x4;

__device__ __forceinline__ unsigned int f2bf(float f) {
    unsigned int u = __float_as_uint(f);
    return (u + 0x7fffu + ((u >> 16) & 1u)) >> 16;   // RNE
}
__device__ __forceinline__ unsigned int pack2(float lo, float hi) {
    return f2bf(lo) | (f2bf(hi) << 16);
}

// ---------------- Pass A: x moments + coarse segment histogram ----------------
__global__ __launch_bounds__(256, 4) void moments_kernel(
    const float* __restrict__ pts, const int* __restrict__ idx,
    float* __restrict__ ws, int* __restrict__ histc, int N, int nb)
{
    __shared__ int lhist[NBMAX];
    __shared__ float red[64];
    for (int t = threadIdx.x; t < nb; t += 256) lhist[t] = 0;

    float S[NIN], M[NMOM];
#pragma unroll
    for (int k = 0; k < NIN; ++k) S[k] = 0.f;
#pragma unroll
    for (int m = 0; m < NMOM; ++m) M[m] = 0.f;
    __syncthreads();

    const int stride = gridDim.x * blockDim.x;
    for (int i = blockIdx.x * blockDim.x + threadIdx.x; i < N; i += stride) {
        const float* p = pts + (size_t)i * NIN;
        atomicAdd(&lhist[idx[i] >> SHIFT], 1);
        float x[NIN];
#pragma unroll
        for (int k = 0; k < NIN; ++k) x[k] = p[k];
        int m = 0;
#pragma unroll
        for (int k = 0; k < NIN; ++k) {
            S[k] += x[k];
#pragma unroll
            for (int l = k; l < NIN; ++l) { M[m] = fmaf(x[k], x[l], M[m]); ++m; }
        }
    }
#pragma unroll
    for (int off = 32; off > 0; off >>= 1) {
#pragma unroll
        for (int k = 0; k < NIN; ++k) S[k] += __shfl_xor(S[k], off, 64);
#pragma unroll
        for (int m = 0; m < NMOM; ++m) M[m] += __shfl_xor(M[m], off, 64);
    }
    if (threadIdx.x < 64) red[threadIdx.x] = 0.f;
    __syncthreads();
    if ((threadIdx.x & 63) == 0) {
#pragma unroll
        for (int k = 0; k < NIN; ++k) atomicAdd(&red[WS_S + k], S[k]);
#pragma unroll
        for (int m = 0; m < NMOM; ++m) atomicAdd(&red[WS_M + m], M[m]);
    }
    __syncthreads();
    if (threadIdx.x < 64) atomicAdd(&ws[threadIdx.x], red[threadIdx.x]);
    for (int t = threadIdx.x; t < nb; t += 256)
        if (lhist[t] > 0) atomicAdd(&histc[t], lhist[t]);
}

// ---------------- coarse scan: offsets[0..nb] + cursor copy ----------------
__global__ void scan_coarse_kernel(const int* __restrict__ histc,
                                   int* __restrict__ offsets,
                                   int* __restrict__ cursor, int nb)
{
    __shared__ int part[256];
    const int tid = threadIdx.x;
    int v[4];
    int sum = 0;
    const int base = tid * 4;
#pragma unroll
    for (int j = 0; j < 4; ++j) {
        const int i = base + j;
        v[j] = (i < nb) ? histc[i] : 0;
        sum += v[j];
    }
    part[tid] = sum;
    __syncthreads();
    for (int d = 1; d < 256; d <<= 1) {
        int t = (tid >= d) ? part[tid - d] : 0;
        __syncthreads();
        part[tid] += t;
        __syncthreads();
    }
    int pre = part[tid] - sum;
#pragma unroll
    for (int j = 0; j < 4; ++j) {
        const int i = base + j;
        if (i < nb) { offsets[i] = pre; cursor[i] = pre; }
        pre += v[j];
    }
    if (tid == 255) offsets[nb] = part[255];
}

// ---------------- finalize kernels ----------------
__global__ void finalize1_kernel(
    const float* __restrict__ w1, const float* __restrict__ b1,
    const float* __restrict__ g1, const float* __restrict__ be1,
    float* __restrict__ ws, float invN)
{
    __shared__ float sc1s[F1];
    const int j = threadIdx.x;
    if (j < F1) {
        float W[NIN];
        float P = 0.f;
#pragma unroll
        for (int k = 0; k < NIN; ++k) {
            W[k] = w1[k * F1 + j];
            P = fmaf(ws[WS_S + k], W[k], P);
        }
        float Q = 0.f;
        int m = 0;
#pragma unroll
        for (int k = 0; k < NIN; ++k) {
            Q = fmaf(ws[WS_M + m], W[k] * W[k], Q); ++m;
#pragma unroll
            for (int l = k + 1; l < NIN; ++l) {
                Q = fmaf(2.f * ws[WS_M + m], W[k] * W[l], Q); ++m;
            }
        }
        const float b = b1[j];
        const float mean = fmaf(P, invN, b);
        const float Eh2 = fmaf(fmaf(2.f * b, P, Q), invN, b * b);
        const float var = Eh2 - mean * mean;
        const float sc = g1[j] * rsqrtf(var + EPS);
        ws[WS_SC1 + j] = sc;
        ws[WS_SH1 + j] = be1[j] - mean * sc;
        sc1s[j] = sc;
    }
    __syncthreads();
    for (int m = threadIdx.x; m < NIN * F1; m += blockDim.x)
        ws[WS_W1P + m] = w1[m] * sc1s[m & (F1 - 1)];
}

__global__ void finalize2_kernel(
    const float* __restrict__ g2, const float* __restrict__ be2,
    const float* __restrict__ b2, float* __restrict__ ws, float invN, float padf)
{
    const int j = threadIdx.x;
    if (j < F2) {
        const float b = b2[j];
        const float S  = ws[WS_S2 + j]  - padf * b;
        const float SS = ws[WS_SS2 + j] - padf * b * b;
        const float mean = S * invN;
        const float var  = SS * invN - mean * mean;
        const float sc   = g2[j] * rsqrtf(var + EPS);
        ws[WS_SC2 + j] = sc;
        ws[WS_SH2 + j] = be2[j] - mean * sc;
    }
}

// f1 (fp32, uniform scalar weights) -> packed bf16 row (32 bf16 = 4 uint4)
__device__ __forceinline__ void f1_row_bf16(
    const float* __restrict__ p, const float* __restrict__ wl,
    const float* __restrict__ sh1, unsigned int* __restrict__ pk /*[16]*/)
{
    float x[NIN];
#pragma unroll
    for (int k = 0; k < NIN; ++k) x[k] = p[k];
#pragma unroll
    for (int fc = 0; fc < 4; ++fc) {
        float h[8];
#pragma unroll
        for (int jj = 0; jj < 8; ++jj) h[jj] = sh1[fc * 8 + jj];
#pragma unroll
        for (int k = 0; k < NIN; ++k) {
            const float xv = x[k];
#pragma unroll
            for (int jj = 0; jj < 8; ++jj)
                h[jj] = fmaf(xv, wl[k * F1 + fc * 8 + jj], h[jj]);
        }
#pragma unroll
        for (int jj = 0; jj < 4; ++jj)
            pk[fc * 4 + jj] = pack2(fmaxf(h[2 * jj], 0.f), fmaxf(h[2 * jj + 1], 0.f));
    }
}

// ---------------- MAIN: f1 materialization (sequential) + fused h2 stats ----------------
__global__ __launch_bounds__(256, 3) void f1stats_kernel(
    const float* __restrict__ pts, const float* __restrict__ w2,
    const float* __restrict__ b2, float* __restrict__ ws,
    uint4* __restrict__ f1buf, int N)
{
    __shared__ __align__(16) unsigned char stag[4][64 * ROWB];
    __shared__ float red[2 * F2];

    const int lane = threadIdx.x & 63, wv = threadIdx.x >> 6;
    const int quad = lane >> 4, m16 = lane & 15;

    bf16x8 bfr[4];
#pragma unroll
    for (int nt = 0; nt < 4; ++nt)
#pragma unroll
        for (int j = 0; j < 8; ++j)
            bfr[nt][j] = (short)f2bf(w2[(quad * 8 + j) * F2 + nt * 16 + m16]);
    float b2f[4];
#pragma unroll
    for (int nt = 0; nt < 4; ++nt) b2f[nt] = b2[nt * 16 + m16];

    const float* wl  = ws + WS_W1P;
    const float* sh1 = ws + WS_SH1;
    const f32x4 zero = {0.f, 0.f, 0.f, 0.f};
    float s[4] = {0.f, 0.f, 0.f, 0.f}, ss[4] = {0.f, 0.f, 0.f, 0.f};

    unsigned char* myst = stag[wv];
    const int nchunks = (N + 63) / 64;
    for (int c = blockIdx.x * 4 + wv; c < nchunks; c += gridDim.x * 4) {
        const int i = c * 64 + lane;
        unsigned int pk[16];
        if (i < N) {
            f1_row_bf16(pts + (size_t)i * NIN, wl, sh1, pk);
        } else {
#pragma unroll
            for (int q = 0; q < 16; ++q) pk[q] = 0u;
        }
        uint4* wrow = (uint4*)(myst + lane * ROWB);
#pragma unroll
        for (int cidx = 0; cidx < 4; ++cidx)
            wrow[cidx] = make_uint4(pk[4*cidx+0], pk[4*cidx+1], pk[4*cidx+2], pk[4*cidx+3]);

        if (i < N) {  // sequential 64B row write, in original point order
            uint4* dst = f1buf + (size_t)i * 4;
            dst[0] = make_uint4(pk[0],  pk[1],  pk[2],  pk[3]);
            dst[1] = make_uint4(pk[4],  pk[5],  pk[6],  pk[7]);
            dst[2] = make_uint4(pk[8],  pk[9],  pk[10], pk[11]);
            dst[3] = make_uint4(pk[12], pk[13], pk[14], pk[15]);
        }

        bf16x8 afr[4];
#pragma unroll
        for (int mt = 0; mt < 4; ++mt)
            afr[mt] = *(const bf16x8*)(myst + (mt * 16 + m16) * ROWB + quad * 16);
#pragma unroll
        for (int mt = 0; mt < 4; ++mt) {
#pragma unroll
            for (int nt = 0; nt < 4; ++nt) {
                f32x4 d = __builtin_amdgcn_mfma_f32_16x16x32_bf16(afr[mt], bfr[nt], zero, 0, 0, 0);
#pragma unroll
                for (int rr = 0; rr < 4; ++rr) {
                    const float v = d[rr] + b2f[nt];
                    s[nt] += v;
                    ss[nt] = fmaf(v, v, ss[nt]);
                }
            }
        }
    }

#pragma unroll
    for (int off = 16; off < 64; off <<= 1)
#pragma unroll
        for (int nt = 0; nt < 4; ++nt) {
            s[nt]  += __shfl_xor(s[nt], off, 64);
            ss[nt] += __shfl_xor(ss[nt], off, 64);
        }
    if (threadIdx.x < 2 * F2) red[threadIdx.x] = 0.f;
    __syncthreads();
    if (quad == 0) {
#pragma unroll
        for (int nt = 0; nt < 4; ++nt) {
            atomicAdd(&red[nt * 16 + m16], s[nt]);
            atomicAdd(&red[F2 + nt * 16 + m16], ss[nt]);
        }
    }
    __syncthreads();
    if (threadIdx.x < F2) {
        atomicAdd(&ws[WS_S2 + threadIdx.x],  red[threadIdx.x]);
        atomicAdd(&ws[WS_SS2 + threadIdx.x], red[F2 + threadIdx.x]);
    }
}

// ---------------- binning: scatter only (pointid, seg) 8B pairs ----------------
__global__ __launch_bounds__(256) void binning_kernel(
    const int* __restrict__ idx, int* __restrict__ cursor,
    int2* __restrict__ pair, int N, int nb)
{
    __shared__ int lcnt[NBMAX];
    __shared__ int runbase[NBMAX];
    const int tid = threadIdx.x;
    const int t0 = blockIdx.x * BT_BIN;
    for (int t = tid; t < nb; t += 256) lcnt[t] = 0;
    __syncthreads();
#pragma unroll 4
    for (int r = 0; r < BT_BIN / 256; ++r) {
        const int i = t0 + r * 256 + tid;
        if (i < N) atomicAdd(&lcnt[idx[i] >> SHIFT], 1);
    }
    __syncthreads();
    for (int t = tid; t < nb; t += 256) {
        const int c = lcnt[t];
        if (c > 0) runbase[t] = atomicAdd(&cursor[t], c);
        lcnt[t] = 0;
    }
    __syncthreads();
#pragma unroll 4
    for (int r = 0; r < BT_BIN / 256; ++r) {
        const int i = t0 + r * 256 + tid;
        if (i < N) {
            const int sg = idx[i];
            const int bb = sg >> SHIFT;
            const int p = runbase[bb] + atomicAdd(&lcnt[bb], 1);
            pair[p] = make_int2(i, sg);
        }
    }
}

// ---------------- MAIN: per-bucket window scatter, gathering f1 rows ----------------
__global__ __launch_bounds__(256, 3) void bucket_scatter_kernel(
    const uint4* __restrict__ f1buf, const int2* __restrict__ pair,
    const float* __restrict__ w2, const float* __restrict__ b2,
    const float* __restrict__ ws, const int* __restrict__ offsets,
    unsigned int* __restrict__ out, int nseg)
{
    __shared__ unsigned int win[NSEGB * WSTRIDE];
    __shared__ int2 prl[4][64];

    const int b = blockIdx.x;
    const int start = offsets[b], end = offsets[b + 1];
    const int tid = threadIdx.x;
    const int lane = tid & 63, wv = tid >> 6;
    const int quad = lane >> 4, m16 = lane & 15;

    for (int t = tid; t < NSEGB * WSTRIDE; t += 256) win[t] = 0u;

    bf16x8 bfr[4];
#pragma unroll
    for (int nt = 0; nt < 4; ++nt)
#pragma unroll
        for (int j = 0; j < 8; ++j)
            bfr[nt][j] = (short)f2bf(w2[(quad * 8 + j) * F2 + nt * 16 + m16]);
    float sc2f[4], shb[4];
#pragma unroll
    for (int nt = 0; nt < 4; ++nt) {
        const int f = nt * 16 + m16;
        sc2f[nt] = ws[WS_SC2 + f];
        shb[nt]  = fmaf(b2[f], sc2f[nt], ws[WS_SH2 + f]);
    }
    const f32x4 zero = {0.f, 0.f, 0.f, 0.f};
    __syncthreads();

    const int segbase = b << SHIFT;
    const int nch = (end - start + 63) >> 6;
    const bf16x8* fb = (const bf16x8*)f1buf;
    for (int c = wv; c < nch; c += 4) {
        const int cbase = start + c * 64;
        const int sp = cbase + lane;
        int2 pr = make_int2(0, -1);
        if (sp < end) {
            pr = pair[sp];
            pr.y -= segbase;
        }
        prl[wv][lane] = pr;

        bf16x8 afr[4];
#pragma unroll
        for (int mt = 0; mt < 4; ++mt) {
            if (cbase + mt * 16 + m16 < end) {
                const int gi = prl[wv][mt * 16 + m16].x;   // quad-broadcast LDS read
                afr[mt] = fb[(size_t)gi * 4 + quad];       // 64B-aligned line-exact gather
            } else {
#pragma unroll
                for (int j = 0; j < 8; ++j) afr[mt][j] = 0;
            }
        }
#pragma unroll
        for (int mt = 0; mt < 4; ++mt) {
            f32x4 d[4];
#pragma unroll
            for (int nt = 0; nt < 4; ++nt)
                d[nt] = __builtin_amdgcn_mfma_f32_16x16x32_bf16(afr[mt], bfr[nt], zero, 0, 0, 0);
#pragma unroll
            for (int rr = 0; rr < 4; ++rr) {
                const int sl = prl[wv][mt * 16 + quad * 4 + rr].y;
                if (sl >= 0) {
#pragma unroll
                    for (int nt = 0; nt < 4; ++nt) {
                        const float v = fmaf(d[nt][rr], sc2f[nt], shb[nt]);
                        if (v > 0.f)
                            atomicMax(&win[sl * WSTRIDE + nt * 16 + m16], __float_as_uint(v));
                    }
                }
            }
        }
    }
    __syncthreads();
    const int rows = min(NSEGB, nseg - segbase);
    for (int t = tid; t < rows * 64; t += 256)
        out[(size_t)(segbase + (t >> 6)) * 64 + (t & 63)] = win[(t >> 6) * WSTRIDE + (t & 63)];
}

// ---------------- FALLBACK: standalone h2 stats (no f1buf) ----------------
__global__ __launch_bounds__(256, 3) void stats2_kernel(
    const float* __restrict__ pts, const float* __restrict__ w2,
    const float* __restrict__ b2, float* __restrict__ ws, int N)
{
    __shared__ __align__(16) unsigned char stag[4][64 * ROWB];
    __shared__ float red[2 * F2];

    const int lane = threadIdx.x & 63, wv = threadIdx.x >> 6;
    const int quad = lane >> 4, m16 = lane & 15;

    bf16x8 bfr[4];
#pragma unroll
    for (int nt = 0; nt < 4; ++nt)
#pragma unroll
        for (int j = 0; j < 8; ++j)
            bfr[nt][j] = (short)f2bf(w2[(quad * 8 + j) * F2 + nt * 16 + m16]);
    float b2f[4];
#pragma unroll
    for (int nt = 0; nt < 4; ++nt) b2f[nt] = b2[nt * 16 + m16];

    const float* wl  = ws + WS_W1P;
    const float* sh1 = ws + WS_SH1;
    const f32x4 zero = {0.f, 0.f, 0.f, 0.f};
    float s[4] = {0.f, 0.f, 0.f, 0.f}, ss[4] = {0.f, 0.f, 0.f, 0.f};

    unsigned char* myst = stag[wv];
    const int nchunks = (N + 63) / 64;
    for (int c = blockIdx.x * 4 + wv; c < nchunks; c += gridDim.x * 4) {
        const int i = c * 64 + lane;
        unsigned int pk[16];
        if (i < N) {
            f1_row_bf16(pts + (size_t)i * NIN, wl, sh1, pk);
        } else {
#pragma unroll
            for (int q = 0; q < 16; ++q) pk[q] = 0u;
        }
        uint4* wrow = (uint4*)(myst + lane * ROWB);
#pragma unroll
        for (int cidx = 0; cidx < 4; ++cidx)
            wrow[cidx] = make_uint4(pk[4*cidx+0], pk[4*cidx+1], pk[4*cidx+2], pk[4*cidx+3]);

        bf16x8 afr[4];
#pragma unroll
        for (int mt = 0; mt < 4; ++mt)
            afr[mt] = *(const bf16x8*)(myst + (mt * 16 + m16) * ROWB + quad * 16);
#pragma unroll
        for (int mt = 0; mt < 4; ++mt) {
#pragma unroll
            for (int nt = 0; nt < 4; ++nt) {
                f32x4 d = __builtin_amdgcn_mfma_f32_16x16x32_bf16(afr[mt], bfr[nt], zero, 0, 0, 0);
#pragma unroll
                for (int rr = 0; rr < 4; ++rr) {
                    const float v = d[rr] + b2f[nt];
                    s[nt] += v;
                    ss[nt] = fmaf(v, v, ss[nt]);
                }
            }
        }
    }
#pragma unroll
    for (int off = 16; off < 64; off <<= 1)
#pragma unroll
        for (int nt = 0; nt < 4; ++nt) {
            s[nt]  += __shfl_xor(s[nt], off, 64);
            ss[nt] += __shfl_xor(ss[nt], off, 64);
        }
    if (threadIdx.x < 2 * F2) red[threadIdx.x] = 0.f;
    __syncthreads();
    if (quad == 0) {
#pragma unroll
        for (int nt = 0; nt < 4; ++nt) {
            atomicAdd(&red[nt * 16 + m16], s[nt]);
            atomicAdd(&red[F2 + nt * 16 + m16], ss[nt]);
        }
    }
    __syncthreads();
    if (threadIdx.x < F2) {
        atomicAdd(&ws[WS_S2 + threadIdx.x],  red[threadIdx.x]);
        atomicAdd(&ws[WS_SS2 + threadIdx.x], red[F2 + threadIdx.x]);
    }
}

// ---------------- FALLBACK: per-bucket window scatter, recomputing f1 from pts ----------------
__global__ __launch_bounds__(256, 2) void bucket_scatter_gather_kernel(
    const float* __restrict__ pts, const int2* __restrict__ pair,
    const float* __restrict__ w2, const float* __restrict__ b2,
    const float* __restrict__ ws, const int* __restrict__ offsets,
    unsigned int* __restrict__ out, int nseg)
{
    __shared__ unsigned int win[NSEGB * WSTRIDE];
    __shared__ __align__(16) unsigned char stag[4][64 * ROWB];
    __shared__ int segl[4][64];

    const int b = blockIdx.x;
    const int start = offsets[b], end = offsets[b + 1];
    const int tid = threadIdx.x;
    const int lane = tid & 63, wv = tid >> 6;
    const int quad = lane >> 4, m16 = lane & 15;

    for (int t = tid; t < NSEGB * WSTRIDE; t += 256) win[t] = 0u;

    bf16x8 bfr[4];
#pragma unroll
    for (int nt = 0; nt < 4; ++nt)
#pragma unroll
        for (int j = 0; j < 8; ++j)
            bfr[nt][j] = (short)f2bf(w2[(quad * 8 + j) * F2 + nt * 16 + m16]);
    float sc2f[4], shb[4];
#pragma unroll
    for (int nt = 0; nt < 4; ++nt) {
        const int f = nt * 16 + m16;
        sc2f[nt] = ws[WS_SC2 + f];
        shb[nt]  = fmaf(b2[f], sc2f[nt], ws[WS_SH2 + f]);
    }
    const float* wl  = ws + WS_W1P;
    const float* sh1 = ws + WS_SH1;
    const f32x4 zero = {0.f, 0.f, 0.f, 0.f};
    __syncthreads();

    const int segbase = b << SHIFT;
    const int nch = (end - start + 63) >> 6;
    unsigned char* myst = stag[wv];
    for (int c = wv; c < nch; c += 4) {
        const int cbase = start + c * 64;
        const int sp = cbase + lane;
        unsigned int pk[16];
        int sl = -1;
        if (sp < end) {
            const int2 pr = pair[sp];
            f1_row_bf16(pts + (size_t)pr.x * NIN, wl, sh1, pk);
            sl = pr.y - segbase;
        } else {
#pragma unroll
            for (int q = 0; q < 16; ++q) pk[q] = 0u;
        }
        segl[wv][lane] = sl;
        uint4* wrow = (uint4*)(myst + lane * ROWB);
#pragma unroll
        for (int cidx = 0; cidx < 4; ++cidx)
            wrow[cidx] = make_uint4(pk[4*cidx+0], pk[4*cidx+1], pk[4*cidx+2], pk[4*cidx+3]);

        bf16x8 afr[4];
#pragma unroll
        for (int mt = 0; mt < 4; ++mt)
            afr[mt] = *(const bf16x8*)(myst + (mt * 16 + m16) * ROWB + quad * 16);
#pragma unroll
        for (int mt = 0; mt < 4; ++mt) {
            f32x4 d[4];
#pragma unroll
            for (int nt = 0; nt < 4; ++nt)
                d[nt] = __builtin_amdgcn_mfma_f32_16x16x32_bf16(afr[mt], bfr[nt], zero, 0, 0, 0);
#pragma unroll
            for (int rr = 0; rr < 4; ++rr) {
                const int sl2 = segl[wv][mt * 16 + quad * 4 + rr];
                if (sl2 >= 0) {
#pragma unroll
                    for (int nt = 0; nt < 4; ++nt) {
                        const float v = fmaf(d[nt][rr], sc2f[nt], shb[nt]);
                        if (v > 0.f)
                            atomicMax(&win[sl2 * WSTRIDE + nt * 16 + m16], __float_as_uint(v));
                    }
                }
            }
        }
    }
    __syncthreads();
    const int rows = min(NSEGB, nseg - segbase);
    for (int t = tid; t < rows * 64; t += 256)
        out[(size_t)(segbase + (t >> 6)) * 64 + (t & 63)] = win[(t >> 6) * WSTRIDE + (t & 63)];
}

extern "C" void kernel_launch(void* const* d_in, const int* in_sizes, int n_in,
                              void* d_out, int out_size, void* d_ws, size_t ws_size,
                              hipStream_t stream)
{
    const float* pts = (const float*)d_in[0];
    const int*   idx = (const int*)d_in[1];
    const float* w1  = (const float*)d_in[3];
    const float* b1  = (const float*)d_in[4];
    const float* g1  = (const float*)d_in[5];
    const float* be1 = (const float*)d_in[6];
    const float* w2  = (const float*)d_in[7];
    const float* b2  = (const float*)d_in[8];
    const float* g2  = (const float*)d_in[9];
    const float* be2 = (const float*)d_in[10];

    const int N = in_sizes[0] / NIN;
    const int nseg = out_size / F2;
    const int nb = (nseg + NSEGB - 1) >> SHIFT;
    const float invN = 1.0f / (float)N;
    const float padf = (float)((64 - (N & 63)) & 63);

    char* base = (char*)d_ws;
    const size_t f1bytes = (size_t)N * 64;
    const size_t pairbytes = (size_t)N * 8;
    const size_t tailbytes = 4096 + ((size_t)NBMAX + NBMAX + 1 + NBMAX) * sizeof(int) + 256;
    const size_t need_main = f1bytes + pairbytes + tailbytes;

    if (ws_size >= need_main) {
        // ---- main path ----
        uint4* f1buf   = (uint4*)base;
        int2*  pair    = (int2*)(base + f1bytes);
        float* ws      = (float*)(base + f1bytes + pairbytes);
        int*   histc   = (int*)(base + f1bytes + pairbytes + 4096);
        int*   offsets = histc + NBMAX;
        int*   cursor  = offsets + NBMAX + 1;

        hipMemsetAsync(ws, 0, 192 * sizeof(float), stream);
        hipMemsetAsync(histc, 0, NBMAX * sizeof(int), stream);

        moments_kernel<<<1024, 256, 0, stream>>>(pts, idx, ws, histc, N, nb);
        finalize1_kernel<<<1, 320, 0, stream>>>(w1, b1, g1, be1, ws, invN);
        scan_coarse_kernel<<<1, 256, 0, stream>>>(histc, offsets, cursor, nb);
        f1stats_kernel<<<1024, 256, 0, stream>>>(pts, w2, b2, ws, f1buf, N);
        binning_kernel<<<(N + BT_BIN - 1) / BT_BIN, 256, 0, stream>>>(
            idx, cursor, pair, N, nb);
        finalize2_kernel<<<1, 64, 0, stream>>>(g2, be2, b2, ws, invN, padf);
        bucket_scatter_kernel<<<nb, 256, 0, stream>>>(
            f1buf, pair, w2, b2, ws, offsets, (unsigned int*)d_out, nseg);
    } else {
        // ---- fallback: no f1 materialization ----
        int2*  pair    = (int2*)base;
        float* ws      = (float*)(base + pairbytes);
        int*   histc   = (int*)(base + pairbytes + 4096);
        int*   offsets = histc + NBMAX;
        int*   cursor  = offsets + NBMAX + 1;

        hipMemsetAsync(ws, 0, 192 * sizeof(float), stream);
        hipMemsetAsync(histc, 0, NBMAX * sizeof(int), stream);

        moments_kernel<<<1024, 256, 0, stream>>>(pts, idx, ws, histc, N, nb);
        finalize1_kernel<<<1, 320, 0, stream>>>(w1, b1, g1, be1, ws, invN);
        scan_coarse_kernel<<<1, 256, 0, stream>>>(histc, offsets, cursor, nb);
        binning_kernel<<<(N + BT_BIN - 1) / BT_BIN, 256, 0, stream>>>(
            idx, cursor, pair, N, nb);
        stats2_kernel<<<1024, 256, 0, stream>>>(pts, w2, b2, ws, N);
        finalize2_kernel<<<1, 64, 0, stream>>>(g2, be2, b2, ws, invN, padf);
        bucket_scatter_gather_kernel<<<nb, 256, 0, stream>>>(
            pts, pair, w2, b2, ws, offsets, (unsigned int*)d_out, nseg);
    }
}